// Round 9
// baseline (933.467 us; speedup 1.0000x reference)
//
#include <hip/hip_runtime.h>
#include <hip/hip_fp16.h>
#include <hip/hip_bf16.h>
#include <math.h>

#define BB 64
#define CC 122
#define TT 500
#define NCOUT 64
#define DD 128
#define HHEADS 8
#define FFDIM 256
#define NLAYER 2
#define EPS 1e-5f
#define SEQ (BB*CC)   // 7808

// ---------------- workspace float offsets ----------------
#define WS_W2T     0u            // 20480 ushort bf16 w2t [kk][co][ci] = 10240 floats used
#define WS_PWT     10240u        // 8192 floats: proj_w transposed [o][d] (free half of W2T rsv)
#define WS_S1      20480u
#define WS_SH1     20544u
#define WS_S2      20608u
#define WS_SH2     20672u
#define WS_WBF     20736u        // 262144 ushorts: bf16 qkv/out/ff1/ff2 weights
#define WS_TOK     151808u       // 7808*128 floats
#define WS_QKVB    1151232u      // 7808*256 ushorts (bf16 q,k) = 999424 floats
#define WS_VTB     2150656u      // 64*128*128 ushorts (bf16 v^T, [b][dh][j]) = 524288 floats
#define WS_GTAB    2674944u      // 512 uints: packed f16 (gelu, delta) pairs over [-8,8]
#define WS_W1S     2675968u      // 1024 floats: bf16 w1s[co][k=32], BN-folded
#define WS_QKVB2   2676992u      // layer-1 qkv double buffer (999424 floats)
#define WS_VTB2    3676416u      // layer-1 v^T double buffer (524288 floats)
// end = 4200704 floats = 16.8 MB

// WBF internal ushort offsets
#define WB_QKV  0u        // l*49152 + e*128 + k
#define WB_OUT  98304u    // l*16384 + e*128 + k
#define WB_FF1  131072u   // l*32768 + e*128 + k
#define WB_FF2  196608u   // l*32768 + e*256 + k

typedef __attribute__((ext_vector_type(8))) short bf16x8;
typedef __attribute__((ext_vector_type(4))) float f32x4;

__device__ __forceinline__ unsigned short f2bf(float f) {
    unsigned int u = __float_as_uint(f);
    unsigned int r = u + 0x7FFFu + ((u >> 16) & 1u);
    return (unsigned short)(r >> 16);
}

// hardware RNE f32->bf16 (gfx950 v_cvt_pk_bf16_f32), bit-identical to f2bf for finite x
__device__ __forceinline__ unsigned pk_bf16(float a, float b) {
    float r;
    asm("v_cvt_pk_bf16_f32 %0, %1, %2" : "=v"(r) : "v"(a), "v"(b));
    return __float_as_uint(r);
}
__device__ __forceinline__ unsigned short f2bf_hw(float f) {
    return (unsigned short)pk_bf16(f, f);
}

// branch-free erf-GELU (A&S 7.1.26)
__device__ __forceinline__ float gelu_fast(float x) {
    float z = fabsf(x) * 0.70710678118654752f;
    float t = __builtin_amdgcn_rcpf(fmaf(0.3275911f, z, 1.0f));
    float p = fmaf(fmaf(fmaf(fmaf(1.061405429f, t, -1.453152027f), t,
                             1.421413741f), t, -0.284496736f), t, 0.254829592f);
    float e = __expf(-z * z);
    float erf_abs = fmaf(-p * t, e, 1.0f);
    float erf_x = copysignf(erf_abs, x);
    return 0.5f * x * (1.0f + erf_x);
}

// table GELU on a pre-scaled index p = x*32+256 (BN folded by caller); 1 b32 gather
__device__ __forceinline__ float gelu_idx(float p, const unsigned* __restrict__ gt) {
    p = fminf(fmaxf(p, 0.0f), 511.999f);
    int i = (int)p;
    float fr = p - (float)i;
    unsigned u = gt[i];
    __half2 h2 = *(__half2*)&u;
    float v0 = __half2float(h2.x);
    float d  = __half2float(h2.y);
    return fmaf(fr, d, v0);
}

__device__ __forceinline__ unsigned ab16(unsigned hi, unsigned lo) {
    return __builtin_amdgcn_alignbit(hi, lo, 16);
}

// h1 row swizzle (chunked geometry). Writer: lr = w*32 + (lg*4+i)*2 + a (+2 for ch0) ->
// lane-varying bits at lr>>3 (lg0), lr>>4 (lg1); column carries ln15b3 via co>>3.
// cp bits = {ln15b3, lg0, lg1} -> 32-bank stores. Reader: lr = tile*16+ln15+kk -> <=2-way.
__device__ __forceinline__ int swzc(int r) {
    return (r & 7) ^ (((r >> 3) & 1) << 1) ^ (((r >> 4) & 1) << 2);
}

// ---------------- prep: fold BN, bf16-ify weights, build tables ----------------
__global__ void prep_kernel(const float* __restrict__ conv1_w, const float* __restrict__ conv1_b,
                            const float* __restrict__ bn1_g, const float* __restrict__ bn1_b,
                            const float* __restrict__ bn1_m, const float* __restrict__ bn1_v,
                            const float* __restrict__ conv2_w, const float* __restrict__ conv2_b,
                            const float* __restrict__ bn2_g, const float* __restrict__ bn2_b,
                            const float* __restrict__ bn2_m, const float* __restrict__ bn2_v,
                            const float* __restrict__ qkv_w, const float* __restrict__ out_w,
                            const float* __restrict__ ff1_w, const float* __restrict__ ff2_w,
                            const float* __restrict__ proj_w,
                            float* __restrict__ ws) {
    int idx = blockIdx.x * blockDim.x + threadIdx.x;
    if (idx < 20480) {
        int ci = idx & 63; int co = (idx >> 6) & 63; int kk = idx >> 12;
        unsigned short* wt = (unsigned short*)(ws + WS_W2T);
        wt[idx] = f2bf(conv2_w[(co*64 + ci)*5 + kk]);
    } else if (idx < 20544) {
        int i = idx - 20480;
        float s = bn1_g[i] * rsqrtf(bn1_v[i] + EPS);
        ws[WS_S1 + i] = s;
        ws[WS_SH1 + i] = (conv1_b[i] - bn1_m[i]) * s + bn1_b[i];
    } else if (idx < 20608) {
        int i = idx - 20544;
        float s = bn2_g[i] * rsqrtf(bn2_v[i] + EPS);
        ws[WS_S2 + i] = s;
        ws[WS_SH2 + i] = (conv2_b[i] - bn2_m[i]) * s + bn2_b[i];
    } else if (idx < 282752) {
        int r = idx - 20608;
        unsigned short* wbf = (unsigned short*)(ws + WS_WBF);
        float v;
        if (r < 98304)       v = qkv_w[r];
        else if (r < 131072) v = out_w[r - 98304];
        else if (r < 196608) v = ff1_w[r - 131072];
        else                 v = ff2_w[r - 196608];
        wbf[r] = f2bf(v);
    } else if (idx < 283264) {
        int i = idx - 282752;
        float x0 = (i - 256) * 0.03125f;
        float x1 = x0 + 0.03125f;
        float g0 = 0.5f*x0*(1.0f + erff(x0*0.70710678118654752f));
        float g1 = 0.5f*x1*(1.0f + erff(x1*0.70710678118654752f));
        __half hv = __float2half_rn(g0);
        __half hd = __float2half_rn(g1 - g0);
        unsigned short uv = *(unsigned short*)&hv;
        unsigned short ud = *(unsigned short*)&hd;
        ((unsigned*)(ws + WS_GTAB))[i] = (unsigned)uv | ((unsigned)ud << 16);
    } else if (idx < 285312) {
        int i = idx - 283264;            // co*32 + k
        int co = i >> 5, k = i & 31;
        unsigned short* w1s = (unsigned short*)(ws + WS_W1S);
        float s = bn1_g[co] * rsqrtf(bn1_v[co] + EPS);
        w1s[i] = (k < 9) ? f2bf(conv1_w[co*9 + k] * s) : (unsigned short)0;
    } else if (idx < 293504) {
        int i = idx - 285312;            // o*128 + d
        int o = i >> 7, d = i & 127;
        ws[WS_PWT + i] = proj_w[d*64 + o];   // transpose for coalesced conv epilogue
    }
}

// ---------------- fused conv1 [MFMA] + pool + conv2 [MFMA] + mean + proj ----------------
// round-9: chunked structure (R8, correctness-verified) with the register budget fixed.
// Spill pattern across rounds: reported arch-VGPR == cap/2 when AGPRs in use (R4 64/128,
// R7 36/72, R8 48/96) -> forced caps starved the arch half. Fix: (a) launch_bounds(256,4)
// (cap 128, never spilled); (b) phase-2 split into two N-passes with acc[2][2] (16 AGPR,
// was 32) + per-pass epilogue so accum lifetime is short -> natural allocation should land
// ~70-90 total -> runtime occupancy 5-7 blocks/CU (LDS 21.3 KB allows 7).
__global__ __launch_bounds__(256, 4) void conv_kernel(const float* __restrict__ x,
            const float* __restrict__ proj_b,
            const float* __restrict__ elec,
            const float* __restrict__ wsr, float* __restrict__ tok) {
    __shared__ __align__(16) unsigned short h1c[132*64];  // 16896 B (132: read-pad rows 130,131)
    __shared__ __align__(16) unsigned short xbf[544];     // 1088 B
    __shared__ __align__(16) unsigned gtab[512];          // 2048 B (packed f16 pairs)
    __shared__ float part[256];                           // 1024 B
    __shared__ float mean_l[64];                          // 256 B
    const int n = blockIdx.x;
    const int c = n % CC;
    const int tid = threadIdx.x;
    const float* xg = x + (size_t)n * TT;

    for (int i = tid; i < 544; i += 256) {
        unsigned short v = 0;
        if (i >= 4 && i < 504) v = f2bf_hw(xg[i-4]);
        xbf[i] = v;
    }
    if (tid < 128) {
        ((uint4*)gtab)[tid] = ((const uint4*)(wsr + WS_GTAB))[tid];
    }
    // zero rows 0,1 (chunk0 low halo) and 130,131 (masked-row read pad)
    if (tid < 128) { h1c[tid] = 0; h1c[130*64 + tid] = 0; }
    __syncthreads();

    const int lane = tid & 63;
    const int w = tid >> 6;
    const int ln15 = lane & 15, lg = lane >> 4;

    const unsigned short* wbase = (const unsigned short*)(wsr + WS_W2T) + ln15*64 + lg*8;
    float psum[4] = {0.f, 0.f, 0.f, 0.f};

    for (int ch = 0; ch < 2; ch++) {
        const int tb = ch ? 248 : 0;          // t base of this chunk
        const int off = ch ? 0 : 2;           // lr = w*32 + (lg*4+i)*2 + a + off
        const int NBc = ch ? 124 : 126;       // valid local out rows this chunk

        // ---- phase 1: conv1 MFMA, stride-4 rows; wave w covers t = tb+w*64 .. +63 ----
        {
            // per-chunk scoped: b1f/shp die at end of this block (register diet)
            const unsigned short* w1s = (const unsigned short*)(wsr + WS_W1S);
            int P = tb + w*64 + ln15*4 + lg*8;          // ushort idx, 8B aligned (tb%4==0)
            uint2 q0 = *(const uint2*)&xbf[P];
            uint2 q1 = *(const uint2*)&xbf[P + 4];
            uint2 q2 = *(const uint2*)&xbf[P + 8];
            unsigned d0 = q0.x, d1 = q0.y, d2 = q1.x, d3 = q1.y, d4 = q2.x, d5 = q2.y;
            unsigned e0 = ab16(d1,d0), e1 = ab16(d2,d1), e2 = ab16(d3,d2),
                     e3 = ab16(d4,d3), e4 = ab16(d5,d4);
            // chunk1: zero rows 126,127 (read as pooled 250,251 pads; stores go to <=125)
            if (ch && tid < 128) h1c[126*64 + tid] = 0;
#pragma unroll
            for (int a = 0; a < 2; a++) {
                union { unsigned u[4]; bf16x8 b; } Ue, Uo;
                if (a == 0) {
                    Ue.u[0]=d0; Ue.u[1]=d1; Ue.u[2]=d2; Ue.u[3]=d3;
                    Uo.u[0]=e0; Uo.u[1]=e1; Uo.u[2]=e2; Uo.u[3]=e3;
                } else {
                    Ue.u[0]=d1; Ue.u[1]=d2; Ue.u[2]=d3; Ue.u[3]=d4;
                    Uo.u[0]=e1; Uo.u[1]=e2; Uo.u[2]=e3; Uo.u[3]=e4;
                }
#pragma unroll
                for (int nt = 0; nt < 4; nt++) {
                    int co = nt*16 + ln15;
                    bf16x8 b1f = *(const bf16x8*)&w1s[co*32 + lg*8];
                    float shp = fmaf(wsr[WS_SH1 + co], 32.0f, 256.0f);
                    f32x4 ce = __builtin_amdgcn_mfma_f32_16x16x32_bf16(Ue.b, b1f,
                                   (f32x4){0.f,0.f,0.f,0.f}, 0, 0, 0);
                    f32x4 cd = __builtin_amdgcn_mfma_f32_16x16x32_bf16(Uo.b, b1f,
                                   (f32x4){0.f,0.f,0.f,0.f}, 0, 0, 0);
#pragma unroll
                    for (int i = 0; i < 4; i++) {
                        int lr = w*32 + (lg*4 + i)*2 + a + off;
                        if (ch == 0 || lr <= 125) {       // ch1: mask pooled 250,251
                            float ge = gelu_idx(fmaf(ce[i], 32.0f, shp), gtab);
                            float go = gelu_idx(fmaf(cd[i], 32.0f, shp), gtab);
                            int cp = (co >> 3) ^ swzc(lr);
                            h1c[lr*64 + cp*8 + (co & 7)] = f2bf_hw(fmaxf(ge, go));
                        }
                    }
                }
            }
        }
        __syncthreads();

        // ---- phase 2: conv2 as 5 shifted GEMMs; two N-passes of acc[2][2] (16 AGPR) ----
#pragma unroll
        for (int np = 0; np < 2; np++) {
            f32x4 acc[2][2];
#pragma unroll
            for (int mi = 0; mi < 2; mi++)
#pragma unroll
                for (int ni = 0; ni < 2; ni++) acc[mi][ni] = (f32x4){0.f, 0.f, 0.f, 0.f};
#pragma unroll
            for (int kk = 0; kk < 5; kk++) {
#pragma unroll
                for (int s = 0; s < 2; s++) {
                    bf16x8 bfv[2];
#pragma unroll
                    for (int ni = 0; ni < 2; ni++)
                        bfv[ni] = *(const bf16x8*)(wbase + kk*4096 + (np*2 + ni)*1024 + s*32);
#pragma unroll
                    for (int mi = 0; mi < 2; mi++) {
                        int lr = (w*2 + mi)*16 + ln15 + kk;   // same expr both chunks
                        int cp = (s*4 + lg) ^ swzc(lr);
                        bf16x8 af = *(const bf16x8*)&h1c[lr*64 + cp*8];
#pragma unroll
                        for (int ni = 0; ni < 2; ni++)
                            acc[mi][ni] = __builtin_amdgcn_mfma_f32_16x16x32_bf16(af, bfv[ni], acc[mi][ni], 0, 0, 0);
                    }
                }
            }
            // per-pass epilogue: BN + GELU + accumulate channel partials (acc dies here)
#pragma unroll
            for (int ni = 0; ni < 2; ni++) {
                int nt = np*2 + ni;
                int co = nt*16 + ln15;
                float sc2 = wsr[WS_S2 + co] * 32.0f;
                float sh2 = fmaf(wsr[WS_SH2 + co], 32.0f, 256.0f);
                float p = 0.f;
#pragma unroll
                for (int mi = 0; mi < 2; mi++) {
                    int obase = (w*2 + mi)*16 + lg*4;
#pragma unroll
                    for (int i = 0; i < 4; i++) {
                        if (obase + i < NBc)
                            p += gelu_idx(fmaf(acc[mi][ni][i], sc2, sh2), gtab);
                    }
                }
                psum[nt] += p;
            }
        }
        __syncthreads();   // buffer reuse safety before next chunk's phase-1 stores
    }

    // ---- reduction + proj ----
#pragma unroll
    for (int nt = 0; nt < 4; nt++) {
        float p = psum[nt];
        p += __shfl_down(p, 32, 64);
        p += __shfl_down(p, 16, 64);
        if (lane < 16) part[w*64 + nt*16 + ln15] = p;
    }
    __syncthreads();
    if (tid < 64) {
        mean_l[tid] = (part[tid] + part[64+tid] + part[128+tid] + part[192+tid]) * (1.0f/250.0f);
    }
    __syncthreads();

    if (tid < DD) {
        int d = tid;
        const float* pwt = wsr + WS_PWT;
        float a = proj_b[d] + elec[c*DD + d];
#pragma unroll 8
        for (int o = 0; o < 64; o++) a = fmaf(mean_l[o], pwt[o*128 + d], a);
        tok[(size_t)n * DD + d] = a;
    }
}

// ---------------- qkv GEMM (layer 0 only): tok[f32] @ qkv_w^T + b -> bf16 qkvb / vtb ----
__global__ __launch_bounds__(256) void qkv_gemm(const float* __restrict__ Aptr,
        const unsigned short* __restrict__ Bbf,
        const float* __restrict__ bias,
        unsigned short* __restrict__ qkvb,        // [7808][256]
        unsigned short* __restrict__ vtb) {       // [b*128+dh][128]
    const int tid = threadIdx.x;
    const int m0 = blockIdx.x * 32;
    const int y  = blockIdx.y;                    // 0:q 1:k 2:v
    const int n0 = y * 128;
    __shared__ __align__(16) unsigned short As[32*128];

    const float* A = Aptr + (size_t)m0 * 128;
    for (int i = tid; i < 1024; i += 256) {
        int m = i >> 5; int kq = (i & 31)*4;
        float4 v = *(const float4*)(A + m*128 + kq);
        int cp = (kq >> 3) ^ (m & 15);
        unsigned p0 = pk_bf16(v.x, v.y);
        unsigned p1 = pk_bf16(v.z, v.w);
        *(uint2*)&As[m*128 + cp*8 + (kq & 7)] = make_uint2(p0, p1);
    }
    __syncthreads();

    const int lane = tid & 63, w = tid >> 6;
    const int ln15 = lane & 15, lg = lane >> 4;
    f32x4 acc[2][2];
#pragma unroll
    for (int mi = 0; mi < 2; mi++)
#pragma unroll
        for (int ni = 0; ni < 2; ni++) acc[mi][ni] = (f32x4){0.f, 0.f, 0.f, 0.f};

    const unsigned short* Bb = Bbf + (size_t)n0 * 128;
#pragma unroll
    for (int kt = 0; kt < 4; kt++) {
        bf16x8 af[2], bfv[2];
#pragma unroll
        for (int mi = 0; mi < 2; mi++) {
            int m = mi*16 + ln15;
            int cp = (kt*4 + lg) ^ (m & 15);
            af[mi] = *(const bf16x8*)&As[m*128 + cp*8];
        }
#pragma unroll
        for (int ni = 0; ni < 2; ni++) {
            int nn = (w*2 + ni)*16 + ln15;
            bfv[ni] = *(const bf16x8*)&Bb[(size_t)nn*128 + kt*32 + lg*8];
        }
#pragma unroll
        for (int mi = 0; mi < 2; mi++)
#pragma unroll
            for (int ni = 0; ni < 2; ni++)
                acc[mi][ni] = __builtin_amdgcn_mfma_f32_16x16x32_bf16(af[mi], bfv[ni], acc[mi][ni], 0, 0, 0);
    }

#pragma unroll
    for (int mi = 0; mi < 2; mi++)
#pragma unroll
        for (int ni = 0; ni < 2; ni++) {
            int nloc = (w*2 + ni)*16 + ln15;
            float bb = bias[n0 + nloc];
#pragma unroll
            for (int i = 0; i < 4; i++) {
                int ml = mi*16 + lg*4 + i;
                int nrow = m0 + ml;
                unsigned short us = f2bf_hw(acc[mi][ni][i] + bb);
                if (y < 2) {
                    qkvb[(size_t)nrow*256 + n0 + nloc] = us;
                } else {
                    int bq = nrow / 122;
                    int j  = nrow - bq*122;
                    vtb[((size_t)(bq*128 + nloc))*128 + j] = us;
                }
            }
        }
}

// ---------------- fused attention + out-proj + LN1 + FF + LN2 (+ next-layer qkv) ----------
__global__ __launch_bounds__(512) void attn_tail(
        const unsigned short* __restrict__ qkvb,
        const unsigned short* __restrict__ vtb,
        const unsigned short* __restrict__ outW, const float* __restrict__ outb,
        float* __restrict__ tok,
        const float* __restrict__ ln1g, const float* __restrict__ ln1b,
        const unsigned short* __restrict__ B1, const float* __restrict__ b1,
        const unsigned short* __restrict__ B2, const float* __restrict__ b2,
        const float* __restrict__ ln2g, const float* __restrict__ ln2b,
        const unsigned short* __restrict__ Bq, const float* __restrict__ bq,
        unsigned short* __restrict__ qkvb_o, unsigned short* __restrict__ vtb_o,
        int do_qkv) {
    __shared__ float Cs[32*129];                               // 16.5 KB
    __shared__ __align__(16) unsigned short Pregion[8*16*128]; // 32 KB
    __shared__ __align__(16) unsigned short ctxs[32*128];      // 8 KB

    const int tid = threadIdx.x;
    const int blk = blockIdx.x;
    const int b = blk >> 2, mq = blk & 3;
    const int m0l = mq * 32;
    const int lane = tid & 63, w = tid >> 6;       // w = 0..7 = head
    const int ln15 = lane & 15, lg = lane >> 4;

    const unsigned short* qb = qkvb + (size_t)b * 122 * 256;
    unsigned short* Pw = Pregion + w * 2048;       // 16 rows x 128 cols bf16

    // ================= attention: head h = w, two 16-row chunks =================
    {
        const int h = w;
#pragma unroll
        for (int mt = 0; mt < 2; mt++) {
            int mrow = m0l + mt*16 + ln15;
            int gr = (mrow < 122) ? mrow : 121;
            bf16x8 af = {0,0,0,0,0,0,0,0};
            if (lg < 2) af = *(const bf16x8*)(qb + gr*256 + h*16 + lg*8);
            // S = Q K^T
            f32x4 S[8];
#pragma unroll
            for (int nt = 0; nt < 8; nt++) {
                int j = nt*16 + ln15;
                int gj = (j < 122) ? j : 121;
                bf16x8 bv = {0,0,0,0,0,0,0,0};
                if (lg < 2) bv = *(const bf16x8*)(qb + gj*256 + 128 + h*16 + lg*8);
                S[nt] = __builtin_amdgcn_mfma_f32_16x16x32_bf16(af, bv,
                            (f32x4){0.f,0.f,0.f,0.f}, 0, 0, 0);
            }
            // softmax
            float sm[4];
#pragma unroll
            for (int i = 0; i < 4; i++) {
                float m_ = -1e30f;
#pragma unroll
                for (int nt = 0; nt < 8; nt++) {
                    float v = S[nt][i] * 0.25f;
                    if (nt == 7 && ln15 >= 10) v = -1e30f;
                    S[nt][i] = v;
                    m_ = fmaxf(m_, v);
                }
                m_ = fmaxf(m_, __shfl_xor(m_, 1, 64));
                m_ = fmaxf(m_, __shfl_xor(m_, 2, 64));
                m_ = fmaxf(m_, __shfl_xor(m_, 4, 64));
                m_ = fmaxf(m_, __shfl_xor(m_, 8, 64));
                float s_ = 0.f;
#pragma unroll
                for (int nt = 0; nt < 8; nt++) {
                    float e = __expf(S[nt][i] - m_);
                    S[nt][i] = e;
                    s_ += e;
                }
                s_ += __shfl_xor(s_, 1, 64);
                s_ += __shfl_xor(s_, 2, 64);
                s_ += __shfl_xor(s_, 4, 64);
                s_ += __shfl_xor(s_, 8, 64);
                sm[i] = s_;
            }
            // P -> Pw (16 rows, A-layout)
#pragma unroll
            for (int nt = 0; nt < 8; nt++)
#pragma unroll
                for (int i = 0; i < 4; i++) {
                    int rp = lg*4 + i;
                    int j = nt*16 + ln15;
                    int cp = (j >> 3) ^ rp;
                    Pw[rp*128 + cp*8 + (j & 7)] = f2bf_hw(S[nt][i]);
                }
            // PV
            f32x4 cacc = (f32x4){0.f,0.f,0.f,0.f};
#pragma unroll
            for (int kt = 0; kt < 4; kt++) {
                bf16x8 bv = *(const bf16x8*)(vtb + ((size_t)(b*128 + h*16 + ln15))*128 + kt*32 + lg*8);
                int m = ln15;
                int cp = (kt*4 + lg) ^ m;
                bf16x8 ap = *(const bf16x8*)&Pw[m*128 + cp*8];
                cacc = __builtin_amdgcn_mfma_f32_16x16x32_bf16(ap, bv, cacc, 0, 0, 0);
            }
            // normalize + write ctx (bf16, A-layout)
#pragma unroll
            for (int i = 0; i < 4; i++) {
                float inv = __builtin_amdgcn_rcpf(sm[i]);
                int rp = mt*16 + lg*4 + i;
                int ccol = h*16 + ln15;
                int cp = (ccol >> 3) ^ (rp & 15);
                ctxs[rp*128 + cp*8 + (ccol & 7)] = f2bf_hw(cacc[i] * inv);
            }
        }
    }
    __syncthreads();

    // ================= out-proj + residual: wave w owns cols w*16..w*16+15 =================
    {
        f32x4 acc[2];
#pragma unroll
        for (int mi = 0; mi < 2; mi++) acc[mi] = (f32x4){0.f,0.f,0.f,0.f};
        int nn = w*16 + ln15;
#pragma unroll
        for (int kt = 0; kt < 4; kt++) {
            bf16x8 bv = *(const bf16x8*)&outW[(size_t)nn*128 + kt*32 + lg*8];
#pragma unroll
            for (int mi = 0; mi < 2; mi++) {
                int m = mi*16 + ln15;
                int cp = (kt*4 + lg) ^ (m & 15);
                bf16x8 afm = *(const bf16x8*)&ctxs[m*128 + cp*8];
                acc[mi] = __builtin_amdgcn_mfma_f32_16x16x32_bf16(afm, bv, acc[mi], 0, 0, 0);
            }
        }
        float bb = outb[nn];
#pragma unroll
        for (int mi = 0; mi < 2; mi++)
#pragma unroll
            for (int i = 0; i < 4; i++) {
                int ml = mi*16 + lg*4 + i;
                int mrow = m0l + ml;
                int grow = b*122 + ((mrow < 122) ? mrow : 121);
                Cs[ml*129 + nn] = acc[mi][i] + bb + tok[(size_t)grow*128 + nn];
            }
    }
    __syncthreads();

    // ================= LN1 -> Cs(f32) + ln1buf(bf16) =================
    unsigned short* ln1buf = Pregion;          // 8 KB
    unsigned short* Hs = Pregion + 4096;       // 16 KB
    {
        int r = tid >> 4, sub = tid & 15;      // 32 rows x 16 lanes x 8 cols
        float s1 = 0.f, s2 = 0.f;
#pragma unroll
        for (int j = 0; j < 8; j++) {
            float vv = Cs[r*129 + sub*8 + j];
            s1 += vv; s2 += vv*vv;
        }
        s1 += __shfl_xor(s1, 1, 64); s2 += __shfl_xor(s2, 1, 64);
        s1 += __shfl_xor(s1, 2, 64); s2 += __shfl_xor(s2, 2, 64);
        s1 += __shfl_xor(s1, 4, 64); s2 += __shfl_xor(s2, 4, 64);
        s1 += __shfl_xor(s1, 8, 64); s2 += __shfl_xor(s2, 8, 64);
        float mu = s1 * (1.0f/128.0f);
        float var = s2 * (1.0f/128.0f) - mu*mu;
        float rstd = rsqrtf(var + EPS);
#pragma unroll
        for (int j = 0; j < 8; j++) {
            int nloc = sub*8 + j;
            float vv = (Cs[r*129 + nloc] - mu) * rstd * ln1g[nloc] + ln1b[nloc];
            Cs[r*129 + nloc] = vv;
            int cp = (nloc >> 3) ^ (r & 15);
            ln1buf[r*128 + cp*8 + (nloc & 7)] = f2bf_hw(vv);
        }
    }
    __syncthreads();

    // ================= ff1 (gelu) -> Hs: wave w owns cols w*32..w*32+31 =================
    {
        f32x4 acc1[2][2];
#pragma unroll
        for (int mi = 0; mi < 2; mi++)
#pragma unroll
            for (int ni = 0; ni < 2; ni++) acc1[mi][ni] = (f32x4){0.f,0.f,0.f,0.f};
#pragma unroll
        for (int kt = 0; kt < 4; kt++) {
            bf16x8 afm[2];
#pragma unroll
            for (int mi = 0; mi < 2; mi++) {
                int m = mi*16 + ln15;
                int cp = (kt*4 + lg) ^ (m & 15);
                afm[mi] = *(const bf16x8*)&ln1buf[m*128 + cp*8];
            }
#pragma unroll
            for (int ni = 0; ni < 2; ni++) {
                int nn = (w*2 + ni)*16 + ln15;
                bf16x8 bv = *(const bf16x8*)&B1[(size_t)nn*128 + kt*32 + lg*8];
#pragma unroll
                for (int mi = 0; mi < 2; mi++)
                    acc1[mi][ni] = __builtin_amdgcn_mfma_f32_16x16x32_bf16(afm[mi], bv, acc1[mi][ni], 0, 0, 0);
            }
        }
#pragma unroll
        for (int ni = 0; ni < 2; ni++) {
            int nn = (w*2 + ni)*16 + ln15;
            float bb = b1[nn];
#pragma unroll
            for (int mi = 0; mi < 2; mi++)
#pragma unroll
                for (int i = 0; i < 4; i++) {
                    int m = mi*16 + lg*4 + i;
                    float v = gelu_fast(acc1[mi][ni][i] + bb);
                    int cp = (nn >> 3) ^ (m & 15);
                    Hs[m*256 + cp*8 + (nn & 7)] = f2bf_hw(v);
                }
        }
    }
    __syncthreads();

    // ================= ff2 + residual: wave w owns cols w*16..w*16+15 =================
    {
        f32x4 acc2[2];
#pragma unroll
        for (int mi = 0; mi < 2; mi++) acc2[mi] = (f32x4){0.f,0.f,0.f,0.f};
        int nn = w*16 + ln15;
#pragma unroll
        for (int kt = 0; kt < 8; kt++) {
            bf16x8 bv = *(const bf16x8*)&B2[(size_t)nn*256 + kt*32 + lg*8];
#pragma unroll
            for (int mi = 0; mi < 2; mi++) {
                int m = mi*16 + ln15;
                int cp = (kt*4 + lg) ^ (m & 15);
                bf16x8 afm = *(const bf16x8*)&Hs[m*256 + cp*8];
                acc2[mi] = __builtin_amdgcn_mfma_f32_16x16x32_bf16(afm, bv, acc2[mi], 0, 0, 0);
            }
        }
        float bb = b2[nn];
#pragma unroll
        for (int mi = 0; mi < 2; mi++)
#pragma unroll
            for (int i = 0; i < 4; i++) {
                int ml = mi*16 + lg*4 + i;
                Cs[ml*129 + nn] = acc2[mi][i] + bb + Cs[ml*129 + nn];
            }
    }
    __syncthreads();

    // ================= LN2 -> tok (+ qbuf staging for next-layer qkv) =================
    {
        int r = tid >> 4, sub = tid & 15;
        float s1 = 0.f, s2 = 0.f;
#pragma unroll
        for (int j = 0; j < 8; j++) {
            float vv = Cs[r*129 + sub*8 + j];
            s1 += vv; s2 += vv*vv;
        }
        s1 += __shfl_xor(s1, 1, 64); s2 += __shfl_xor(s2, 1, 64);
        s1 += __shfl_xor(s1, 2, 64); s2 += __shfl_xor(s2, 2, 64);
        s1 += __shfl_xor(s1, 4, 64); s2 += __shfl_xor(s2, 4, 64);
        s1 += __shfl_xor(s1, 8, 64); s2 += __shfl_xor(s2, 8, 64);
        float mu = s1 * (1.0f/128.0f);
        float var = s2 * (1.0f/128.0f) - mu*mu;
        float rstd = rsqrtf(var + EPS);
        bool rowok = (m0l + r < 122);
#pragma unroll
        for (int j = 0; j < 8; j++) {
            int nloc = sub*8 + j;
            float vv = (Cs[r*129 + nloc] - mu) * rstd * ln2g[nloc] + ln2b[nloc];
            if (rowok)
                tok[((size_t)(b*122 + m0l + r))*128 + nloc] = vv;
            if (do_qkv) {
                int cp = (nloc >> 3) ^ (r & 15);
                Pregion[r*128 + cp*8 + (nloc & 7)] = f2bf_hw(vv);
            }
        }
    }

    // ================= next-layer qkv: M=32, N=384, K=128; wave w owns cols w*48.. =====
    if (do_qkv) {
        __syncthreads();
        const unsigned short* qbuf = Pregion;
        f32x4 accq[2][3];
#pragma unroll
        for (int mi = 0; mi < 2; mi++)
#pragma unroll
            for (int ni = 0; ni < 3; ni++) accq[mi][ni] = (f32x4){0.f,0.f,0.f,0.f};
#pragma unroll
        for (int kt = 0; kt < 4; kt++) {
            bf16x8 afm[2];
#pragma unroll
            for (int mi = 0; mi < 2; mi++) {
                int m = mi*16 + ln15;
                int cp = (kt*4 + lg) ^ (m & 15);
                afm[mi] = *(const bf16x8*)&qbuf[m*128 + cp*8];
            }
#pragma unroll
            for (int ni = 0; ni < 3; ni++) {
                int e = w*48 + ni*16 + ln15;
                bf16x8 bv = *(const bf16x8*)&Bq[(size_t)e*128 + kt*32 + lg*8];
#pragma unroll
                for (int mi = 0; mi < 2; mi++)
                    accq[mi][ni] = __builtin_amdgcn_mfma_f32_16x16x32_bf16(afm[mi], bv, accq[mi][ni], 0, 0, 0);
            }
        }
#pragma unroll
        for (int ni = 0; ni < 3; ni++) {
            int e = w*48 + ni*16 + ln15;
            float bb = bq[e];
#pragma unroll
            for (int mi = 0; mi < 2; mi++)
#pragma unroll
                for (int i = 0; i < 4; i++) {
                    int ml = mi*16 + lg*4 + i;
                    int mrow = m0l + ml;
                    if (mrow < 122) {
                        unsigned short us = f2bf_hw(accq[mi][ni][i] + bb);
                        int nrow = b*122 + mrow;
                        if (e < 256)
                            qkvb_o[(size_t)nrow*256 + e] = us;
                        else
                            vtb_o[((size_t)(b*128 + (e - 256)))*128 + mrow] = us;
                    }
                }
        }
    }
}

// ---------------- final: mean over C + subject head ----------------
__global__ __launch_bounds__(128) void final_kernel(const float* __restrict__ tok,
        const int* __restrict__ sid,
        const float* __restrict__ hw, const float* __restrict__ hb,
        float* __restrict__ outp) {
    __shared__ float pool[DD];
    int b = blockIdx.x, tid = threadIdx.x;
    float s = 0.f;
    for (int c2 = 0; c2 < CC; c2++) s += tok[((size_t)b*CC + c2)*DD + tid];
    pool[tid] = s * (1.0f/(float)CC);
    __syncthreads();
    if (tid < 4) {
        int sb = sid[b];
        const float* w = hw + ((size_t)sb*4 + tid)*DD;
        float a = hb[sb*4 + tid];
#pragma unroll 8
        for (int d = 0; d < DD; d++) a = fmaf(pool[d], w[d], a);
        outp[b*4 + tid] = a;
    }
}

extern "C" void kernel_launch(void* const* d_in, const int* in_sizes, int n_in,
                              void* d_out, int out_size, void* d_ws, size_t ws_size,
                              hipStream_t stream) {
    const float* x       = (const float*)d_in[0];
    const int*   sid     = (const int*)  d_in[1];
    const float* conv1_w = (const float*)d_in[2];
    const float* conv1_b = (const float*)d_in[3];
    const float* bn1_g   = (const float*)d_in[4];
    const float* bn1_b   = (const float*)d_in[5];
    const float* bn1_m   = (const float*)d_in[6];
    const float* bn1_v   = (const float*)d_in[7];
    const float* conv2_w = (const float*)d_in[8];
    const float* conv2_b = (const float*)d_in[9];
    const float* bn2_g   = (const float*)d_in[10];
    const float* bn2_b   = (const float*)d_in[11];
    const float* bn2_m   = (const float*)d_in[12];
    const float* bn2_v   = (const float*)d_in[13];
    const float* proj_w  = (const float*)d_in[14];
    const float* proj_b  = (const float*)d_in[15];
    const float* elec    = (const float*)d_in[16];
    const float* qkv_w   = (const float*)d_in[17];
    const float* qkv_b   = (const float*)d_in[18];
    const float* out_w   = (const float*)d_in[19];
    const float* out_b   = (const float*)d_in[20];
    const float* ln1_g   = (const float*)d_in[21];
    const float* ln1_b   = (const float*)d_in[22];
    const float* ff1_w   = (const float*)d_in[23];
    const float* ff1_b   = (const float*)d_in[24];
    const float* ff2_w   = (const float*)d_in[25];
    const float* ff2_b   = (const float*)d_in[26];
    const float* ln2_g   = (const float*)d_in[27];
    const float* ln2_b   = (const float*)d_in[28];
    const float* heads_w = (const float*)d_in[29];
    const float* heads_b = (const float*)d_in[30];
    float* ws = (float*)d_ws;
    const unsigned short* wbf = (const unsigned short*)(ws + WS_WBF);
    unsigned short* qkvb  = (unsigned short*)(ws + WS_QKVB);
    unsigned short* vtb   = (unsigned short*)(ws + WS_VTB);
    unsigned short* qkvb2 = (unsigned short*)(ws + WS_QKVB2);
    unsigned short* vtb2  = (unsigned short*)(ws + WS_VTB2);

    prep_kernel<<<(293504 + 255)/256, 256, 0, stream>>>(
        conv1_w, conv1_b, bn1_g, bn1_b, bn1_m, bn1_v,
        conv2_w, conv2_b, bn2_g, bn2_b, bn2_m, bn2_v,
        qkv_w, out_w, ff1_w, ff2_w, proj_w, ws);

    conv_kernel<<<SEQ, 256, 0, stream>>>(x, proj_b, elec, ws, ws + WS_TOK);

    // layer-0 qkv
    qkv_gemm<<<dim3(244,3), 256, 0, stream>>>(
        ws + WS_TOK, wbf + WB_QKV, qkv_b, qkvb, vtb);

    // layer 0 (emits layer-1 qkv into double buffers)
    attn_tail<<<BB*4, 512, 0, stream>>>(
        qkvb, vtb,
        wbf + WB_OUT, out_b,
        ws + WS_TOK, ln1_g, ln1_b,
        wbf + WB_FF1, ff1_b,
        wbf + WB_FF2, ff2_b,
        ln2_g, ln2_b,
        wbf + WB_QKV + 49152, qkv_b + 384, qkvb2, vtb2, 1);

    // layer 1 (no next layer)
    attn_tail<<<BB*4, 512, 0, stream>>>(
        qkvb2, vtb2,
        wbf + WB_OUT + 16384, out_b + 128,
        ws + WS_TOK, ln1_g + 128, ln1_b + 128,
        wbf + WB_FF1 + 32768, ff1_b + 256,
        wbf + WB_FF2 + 32768, ff2_b + 128,
        ln2_g + 128, ln2_b + 128,
        wbf + WB_QKV, qkv_b, qkvb2, vtb2, 0);

    final_kernel<<<BB, 128, 0, stream>>>(ws + WS_TOK, sid, heads_w, heads_b, (float*)d_out);
}

// Round 10
// 419.478 us; speedup vs baseline: 2.2253x; 2.2253x over previous
//
#include <hip/hip_runtime.h>
#include <hip/hip_fp16.h>
#include <hip/hip_bf16.h>
#include <math.h>

#define BB 64
#define CC 122
#define TT 500
#define NCOUT 64
#define DD 128
#define HHEADS 8
#define FFDIM 256
#define NLAYER 2
#define EPS 1e-5f
#define SEQ (BB*CC)   // 7808

// ---------------- workspace float offsets ----------------
#define WS_W2T     0u            // 20480 ushort bf16 w2t [kk][co][ci] = 10240 floats used
#define WS_PWT     10240u        // 8192 floats: proj_w transposed [o][d] (free half of W2T rsv)
#define WS_S1      20480u
#define WS_SH1     20544u
#define WS_S2      20608u
#define WS_SH2     20672u
#define WS_WBF     20736u        // 262144 ushorts: bf16 qkv/out/ff1/ff2 weights
#define WS_TOK     151808u       // 7808*128 floats
#define WS_QKVB    1151232u      // 7808*256 ushorts (bf16 q,k) = 999424 floats
#define WS_VTB     2150656u      // 64*128*128 ushorts (bf16 v^T, [b][dh][j]) = 524288 floats
#define WS_GTAB    2674944u      // 512 uints: packed f16 (gelu, delta) pairs over [-8,8]
#define WS_W1S     2675968u      // 1024 floats: bf16 w1s[co][k=32], BN-folded
#define WS_QKVB2   2676992u      // layer-1 qkv double buffer (999424 floats)
#define WS_VTB2    3676416u      // layer-1 v^T double buffer (524288 floats)
// end = 4200704 floats = 16.8 MB

// WBF internal ushort offsets
#define WB_QKV  0u        // l*49152 + e*128 + k
#define WB_OUT  98304u    // l*16384 + e*128 + k
#define WB_FF1  131072u   // l*32768 + e*128 + k
#define WB_FF2  196608u   // l*32768 + e*256 + k

typedef __attribute__((ext_vector_type(8))) short bf16x8;
typedef __attribute__((ext_vector_type(4))) float f32x4;

__device__ __forceinline__ unsigned short f2bf(float f) {
    unsigned int u = __float_as_uint(f);
    unsigned int r = u + 0x7FFFu + ((u >> 16) & 1u);
    return (unsigned short)(r >> 16);
}

// hardware RNE f32->bf16 (gfx950 v_cvt_pk_bf16_f32), bit-identical to f2bf for finite x
__device__ __forceinline__ unsigned pk_bf16(float a, float b) {
    float r;
    asm("v_cvt_pk_bf16_f32 %0, %1, %2" : "=v"(r) : "v"(a), "v"(b));
    return __float_as_uint(r);
}
__device__ __forceinline__ unsigned short f2bf_hw(float f) {
    return (unsigned short)pk_bf16(f, f);
}

// branch-free erf-GELU (A&S 7.1.26)
__device__ __forceinline__ float gelu_fast(float x) {
    float z = fabsf(x) * 0.70710678118654752f;
    float t = __builtin_amdgcn_rcpf(fmaf(0.3275911f, z, 1.0f));
    float p = fmaf(fmaf(fmaf(fmaf(1.061405429f, t, -1.453152027f), t,
                             1.421413741f), t, -0.284496736f), t, 0.254829592f);
    float e = __expf(-z * z);
    float erf_abs = fmaf(-p * t, e, 1.0f);
    float erf_x = copysignf(erf_abs, x);
    return 0.5f * x * (1.0f + erf_x);
}

// table GELU on a pre-scaled index p = x*32+256 (BN folded by caller); 1 b32 gather
__device__ __forceinline__ float gelu_idx(float p, const unsigned* __restrict__ gt) {
    p = fminf(fmaxf(p, 0.0f), 511.999f);
    int i = (int)p;
    float fr = p - (float)i;
    unsigned u = gt[i];
    __half2 h2 = *(__half2*)&u;
    float v0 = __half2float(h2.x);
    float d  = __half2float(h2.y);
    return fmaf(fr, d, v0);
}

// h1s row swizzle. Writer (phase 1): r = w*64+lg*16+i*4+a+2 -> lane bits r>>4=lg0, r>>5=lg1;
// column contributes ln15b3 via co>>3. cp bits = {ln15b3, lg0, lg1} -> 32 banks, 2/bank (free).
// Reader (phase 2): r = base+ln15+kk -> r&7 lane-varying, <=2-way. Writer/reader must match.
__device__ __forceinline__ int swz3(int r) {
    return (r & 7) ^ (((r >> 4) & 1) << 1) ^ (((r >> 5) & 1) << 2);
}

// ---------------- prep: fold BN, bf16-ify weights, build tables ----------------
__global__ void prep_kernel(const float* __restrict__ conv1_w, const float* __restrict__ conv1_b,
                            const float* __restrict__ bn1_g, const float* __restrict__ bn1_b,
                            const float* __restrict__ bn1_m, const float* __restrict__ bn1_v,
                            const float* __restrict__ conv2_w, const float* __restrict__ conv2_b,
                            const float* __restrict__ bn2_g, const float* __restrict__ bn2_b,
                            const float* __restrict__ bn2_m, const float* __restrict__ bn2_v,
                            const float* __restrict__ qkv_w, const float* __restrict__ out_w,
                            const float* __restrict__ ff1_w, const float* __restrict__ ff2_w,
                            const float* __restrict__ proj_w,
                            float* __restrict__ ws) {
    int idx = blockIdx.x * blockDim.x + threadIdx.x;
    if (idx < 20480) {
        int ci = idx & 63; int co = (idx >> 6) & 63; int kk = idx >> 12;
        unsigned short* wt = (unsigned short*)(ws + WS_W2T);
        wt[idx] = f2bf(conv2_w[(co*64 + ci)*5 + kk]);
    } else if (idx < 20544) {
        int i = idx - 20480;
        float s = bn1_g[i] * rsqrtf(bn1_v[i] + EPS);
        ws[WS_S1 + i] = s;
        ws[WS_SH1 + i] = (conv1_b[i] - bn1_m[i]) * s + bn1_b[i];
    } else if (idx < 20608) {
        int i = idx - 20544;
        float s = bn2_g[i] * rsqrtf(bn2_v[i] + EPS);
        ws[WS_S2 + i] = s;
        ws[WS_SH2 + i] = (conv2_b[i] - bn2_m[i]) * s + bn2_b[i];
    } else if (idx < 282752) {
        int r = idx - 20608;
        unsigned short* wbf = (unsigned short*)(ws + WS_WBF);
        float v;
        if (r < 98304)       v = qkv_w[r];
        else if (r < 131072) v = out_w[r - 98304];
        else if (r < 196608) v = ff1_w[r - 131072];
        else                 v = ff2_w[r - 196608];
        wbf[r] = f2bf(v);
    } else if (idx < 283264) {
        int i = idx - 282752;
        float x0 = (i - 256) * 0.03125f;
        float x1 = x0 + 0.03125f;
        float g0 = 0.5f*x0*(1.0f + erff(x0*0.70710678118654752f));
        float g1 = 0.5f*x1*(1.0f + erff(x1*0.70710678118654752f));
        __half hv = __float2half_rn(g0);
        __half hd = __float2half_rn(g1 - g0);
        unsigned short uv = *(unsigned short*)&hv;
        unsigned short ud = *(unsigned short*)&hd;
        ((unsigned*)(ws + WS_GTAB))[i] = (unsigned)uv | ((unsigned)ud << 16);
    } else if (idx < 285312) {
        int i = idx - 283264;            // co*32 + k
        int co = i >> 5, k = i & 31;
        unsigned short* w1s = (unsigned short*)(ws + WS_W1S);
        float s = bn1_g[co] * rsqrtf(bn1_v[co] + EPS);
        w1s[i] = (k < 9) ? f2bf(conv1_w[co*9 + k] * s) : (unsigned short)0;
    } else if (idx < 293504) {
        int i = idx - 285312;            // o*128 + d
        int o = i >> 7, d = i & 127;
        ws[WS_PWT + i] = proj_w[d*64 + o];   // transpose for coalesced conv epilogue
    }
}

// ---------------- fused conv1 [MFMA] + pool + conv2 [MFMA] + mean + proj ----------------
// round-10: REVERT to R4 exactly (session-best: conv 256.5us, total 418.9us, zero spill).
// Post-mortem note for future rounds: the chunked-T variants (R7/R8/R9: half-size h1 buffer
// + for(ch) loop for 5-7 blocks/CU) all produced ~2 GB/dispatch scratch spill regardless of
// launch_bounds (7/5/4) or accumulator size (32/32/16 AGPR) -- the compiler mis-allocates
// around the runtime-trip chunk loop with internal barriers. DO NOT retry chunking at HIP
// level. R4's structure is LDS-pinned at 4 blocks/CU (38.4 KB); 512-thread variants failed
// in the prior session (spill / no occupancy gain); gelu pipe-trades are zero-sum (R5);
// swizzle work converged (residual 2.26e7 conflicts = inherent gtab gathers).
__global__ __launch_bounds__(256, 4) void conv_kernel(const float* __restrict__ x,
            const float* __restrict__ proj_b,
            const float* __restrict__ elec,
            const float* __restrict__ wsr, float* __restrict__ tok) {
    __shared__ __align__(16) unsigned short h1s[264*64];  // 33792 B
    __shared__ __align__(16) unsigned short xbf[544];     // 1088 B
    __shared__ __align__(16) unsigned gtab[512];          // 2048 B (packed f16 pairs)
    __shared__ float part[256];                           // 1024 B
    __shared__ float mean_l[64];                          // 256 B
    int n = blockIdx.x;
    int c = n % CC;
    int tid = threadIdx.x;
    const float* xg = x + (size_t)n * TT;

    for (int i = tid; i < 544; i += 256) {
        unsigned short v = 0;
        if (i >= 4 && i < 504) v = f2bf_hw(xg[i-4]);
        xbf[i] = v;
    }
    if (tid < 128) {
        ((uint4*)gtab)[tid] = ((const uint4*)(wsr + WS_GTAB))[tid];
    }
    for (int idx = tid; idx < 14*64; idx += 256) {
        int rr = idx >> 6;
        int r = (rr < 2) ? rr : (rr - 2 + 252);
        h1s[r*64 + (idx & 63)] = 0;
    }
    __syncthreads();

    int lane = tid & 63;
    int w = tid >> 6;
    int ln15 = lane & 15, lg = lane >> 4;

    // ---- phase 1: conv1 via MFMA, strided-row im2col ----
    // MFMA row m <- t = w*128 + m*8 + s  (s = 0..7). Lane window = xbf[P .. P+14],
    // P = w*128 + ln15*8 + lg*8 (16B aligned). Pool pairs (s even, s odd).
    {
        const unsigned short* w1s = (const unsigned short*)(wsr + WS_W1S);
        bf16x8 b1f[4];
        float shp[4];
#pragma unroll
        for (int nt = 0; nt < 4; nt++) {
            int co = nt*16 + ln15;
            b1f[nt] = *(const bf16x8*)&w1s[co*32 + lg*8];
            shp[nt] = fmaf(wsr[WS_SH1 + co], 32.0f, 256.0f);   // BN shift folded into gelu index
        }
        int P = w*128 + ln15*8 + lg*8;
        uint4 Va = *(const uint4*)&xbf[P];
        uint4 Vb = *(const uint4*)&xbf[P + 8];
        unsigned vwin[8] = {Va.x, Va.y, Va.z, Va.w, Vb.x, Vb.y, Vb.z, Vb.w};
#pragma unroll
        for (int a = 0; a < 4; a++) {
            union { unsigned u[4]; bf16x8 b; } Ue, Uo;
#pragma unroll
            for (int d = 0; d < 4; d++) {
                Ue.u[d] = vwin[a + d];                                   // s = 2a   (even)
                Uo.u[d] = (vwin[a + d] >> 16) | (vwin[a + d + 1] << 16); // s = 2a+1 (odd)
            }
            f32x4 ce[4], cod[4];
#pragma unroll
            for (int nt = 0; nt < 4; nt++) {
                ce[nt]  = __builtin_amdgcn_mfma_f32_16x16x32_bf16(Ue.b, b1f[nt],
                              (f32x4){0.f,0.f,0.f,0.f}, 0, 0, 0);
                cod[nt] = __builtin_amdgcn_mfma_f32_16x16x32_bf16(Uo.b, b1f[nt],
                              (f32x4){0.f,0.f,0.f,0.f}, 0, 0, 0);
            }
#pragma unroll
            for (int nt = 0; nt < 4; nt++) {
                int co = nt*16 + ln15;
#pragma unroll
                for (int i = 0; i < 4; i++) {
                    int tp = w*64 + lg*16 + i*4 + a;     // pooled t index
                    if (tp < 250) {
                        float ge = gelu_idx(fmaf(ce[nt][i],  32.0f, shp[nt]), gtab);
                        float go = gelu_idx(fmaf(cod[nt][i], 32.0f, shp[nt]), gtab);
                        int r = tp + 2;
                        int cp = (co >> 3) ^ swz3(r);
                        h1s[r*64 + cp*8 + (co & 7)] = f2bf_hw(fmaxf(ge, go));
                    }
                }
            }
        }
    }
    __syncthreads();

    // ---- phase 2: conv2 as 5 shifted GEMMs ----
    const unsigned short* wt = (const unsigned short*)(wsr + WS_W2T);
    f32x4 acc[4][4];
#pragma unroll
    for (int mi = 0; mi < 4; mi++)
#pragma unroll
        for (int nt = 0; nt < 4; nt++) acc[mi][nt] = (f32x4){0.f, 0.f, 0.f, 0.f};

    const unsigned short* wbase = wt + ln15*64 + lg*8;
#pragma unroll
    for (int kk = 0; kk < 5; kk++) {
#pragma unroll
        for (int s = 0; s < 2; s++) {
            bf16x8 bfv[4];
#pragma unroll
            for (int nt = 0; nt < 4; nt++)
                bfv[nt] = *(const bf16x8*)(wbase + kk*4096 + nt*1024 + s*32);
#pragma unroll
            for (int mi = 0; mi < 4; mi++) {
                int r = (w*4 + mi)*16 + ln15 + kk;
                int cp = (s*4 + lg) ^ swz3(r);
                bf16x8 af = *(const bf16x8*)&h1s[r*64 + cp*8];
#pragma unroll
                for (int nt = 0; nt < 4; nt++)
                    acc[mi][nt] = __builtin_amdgcn_mfma_f32_16x16x32_bf16(af, bfv[nt], acc[mi][nt], 0, 0, 0);
            }
        }
    }

    // ---- epilogue: BN + GELU + mean over t ----
#pragma unroll
    for (int nt = 0; nt < 4; nt++) {
        int co2 = nt*16 + ln15;
        float sc = wsr[WS_S2 + co2] * 32.0f;
        float sh = fmaf(wsr[WS_SH2 + co2], 32.0f, 256.0f);
        float p = 0.f;
#pragma unroll
        for (int mi = 0; mi < 4; mi++) {
            int tbase = (w*4 + mi)*16 + lg*4;
#pragma unroll
            for (int i = 0; i < 4; i++) {
                if (tbase + i < 250)
                    p += gelu_idx(fmaf(acc[mi][nt][i], sc, sh), gtab);
            }
        }
        p += __shfl_down(p, 32, 64);
        p += __shfl_down(p, 16, 64);
        if (lane < 16) part[w*64 + co2] = p;
    }
    __syncthreads();
    if (tid < 64) {
        mean_l[tid] = (part[tid] + part[64+tid] + part[128+tid] + part[192+tid]) * (1.0f/250.0f);
    }
    __syncthreads();

    if (tid < DD) {
        int d = tid;
        const float* pwt = wsr + WS_PWT;
        float a = proj_b[d] + elec[c*DD + d];
#pragma unroll 8
        for (int o = 0; o < 64; o++) a = fmaf(mean_l[o], pwt[o*128 + d], a);
        tok[(size_t)n * DD + d] = a;
    }
}

// ---------------- qkv GEMM (layer 0 only): tok[f32] @ qkv_w^T + b -> bf16 qkvb / vtb ----
__global__ __launch_bounds__(256) void qkv_gemm(const float* __restrict__ Aptr,
        const unsigned short* __restrict__ Bbf,
        const float* __restrict__ bias,
        unsigned short* __restrict__ qkvb,        // [7808][256]
        unsigned short* __restrict__ vtb) {       // [b*128+dh][128]
    const int tid = threadIdx.x;
    const int m0 = blockIdx.x * 32;
    const int y  = blockIdx.y;                    // 0:q 1:k 2:v
    const int n0 = y * 128;
    __shared__ __align__(16) unsigned short As[32*128];

    const float* A = Aptr + (size_t)m0 * 128;
    for (int i = tid; i < 1024; i += 256) {
        int m = i >> 5; int kq = (i & 31)*4;
        float4 v = *(const float4*)(A + m*128 + kq);
        int cp = (kq >> 3) ^ (m & 15);
        unsigned p0 = pk_bf16(v.x, v.y);
        unsigned p1 = pk_bf16(v.z, v.w);
        *(uint2*)&As[m*128 + cp*8 + (kq & 7)] = make_uint2(p0, p1);
    }
    __syncthreads();

    const int lane = tid & 63, w = tid >> 6;
    const int ln15 = lane & 15, lg = lane >> 4;
    f32x4 acc[2][2];
#pragma unroll
    for (int mi = 0; mi < 2; mi++)
#pragma unroll
        for (int ni = 0; ni < 2; ni++) acc[mi][ni] = (f32x4){0.f, 0.f, 0.f, 0.f};

    const unsigned short* Bb = Bbf + (size_t)n0 * 128;
#pragma unroll
    for (int kt = 0; kt < 4; kt++) {
        bf16x8 af[2], bfv[2];
#pragma unroll
        for (int mi = 0; mi < 2; mi++) {
            int m = mi*16 + ln15;
            int cp = (kt*4 + lg) ^ (m & 15);
            af[mi] = *(const bf16x8*)&As[m*128 + cp*8];
        }
#pragma unroll
        for (int ni = 0; ni < 2; ni++) {
            int nn = (w*2 + ni)*16 + ln15;
            bfv[ni] = *(const bf16x8*)&Bb[(size_t)nn*128 + kt*32 + lg*8];
        }
#pragma unroll
        for (int mi = 0; mi < 2; mi++)
#pragma unroll
            for (int ni = 0; ni < 2; ni++)
                acc[mi][ni] = __builtin_amdgcn_mfma_f32_16x16x32_bf16(af[mi], bfv[ni], acc[mi][ni], 0, 0, 0);
    }

#pragma unroll
    for (int mi = 0; mi < 2; mi++)
#pragma unroll
        for (int ni = 0; ni < 2; ni++) {
            int nloc = (w*2 + ni)*16 + ln15;
            float bb = bias[n0 + nloc];
#pragma unroll
            for (int i = 0; i < 4; i++) {
                int ml = mi*16 + lg*4 + i;
                int nrow = m0 + ml;
                unsigned short us = f2bf_hw(acc[mi][ni][i] + bb);
                if (y < 2) {
                    qkvb[(size_t)nrow*256 + n0 + nloc] = us;
                } else {
                    int bq = nrow / 122;
                    int j  = nrow - bq*122;
                    vtb[((size_t)(bq*128 + nloc))*128 + j] = us;
                }
            }
        }
}

// ---------------- fused attention + out-proj + LN1 + FF + LN2 (+ next-layer qkv) ----------
__global__ __launch_bounds__(512) void attn_tail(
        const unsigned short* __restrict__ qkvb,
        const unsigned short* __restrict__ vtb,
        const unsigned short* __restrict__ outW, const float* __restrict__ outb,
        float* __restrict__ tok,
        const float* __restrict__ ln1g, const float* __restrict__ ln1b,
        const unsigned short* __restrict__ B1, const float* __restrict__ b1,
        const unsigned short* __restrict__ B2, const float* __restrict__ b2,
        const float* __restrict__ ln2g, const float* __restrict__ ln2b,
        const unsigned short* __restrict__ Bq, const float* __restrict__ bq,
        unsigned short* __restrict__ qkvb_o, unsigned short* __restrict__ vtb_o,
        int do_qkv) {
    __shared__ float Cs[32*129];                               // 16.5 KB
    __shared__ __align__(16) unsigned short Pregion[8*16*128]; // 32 KB
    __shared__ __align__(16) unsigned short ctxs[32*128];      // 8 KB

    const int tid = threadIdx.x;
    const int blk = blockIdx.x;
    const int b = blk >> 2, mq = blk & 3;
    const int m0l = mq * 32;
    const int lane = tid & 63, w = tid >> 6;       // w = 0..7 = head
    const int ln15 = lane & 15, lg = lane >> 4;

    const unsigned short* qb = qkvb + (size_t)b * 122 * 256;
    unsigned short* Pw = Pregion + w * 2048;       // 16 rows x 128 cols bf16

    // ================= attention: head h = w, two 16-row chunks =================
    {
        const int h = w;
#pragma unroll
        for (int mt = 0; mt < 2; mt++) {
            int mrow = m0l + mt*16 + ln15;
            int gr = (mrow < 122) ? mrow : 121;
            bf16x8 af = {0,0,0,0,0,0,0,0};
            if (lg < 2) af = *(const bf16x8*)(qb + gr*256 + h*16 + lg*8);
            // S = Q K^T
            f32x4 S[8];
#pragma unroll
            for (int nt = 0; nt < 8; nt++) {
                int j = nt*16 + ln15;
                int gj = (j < 122) ? j : 121;
                bf16x8 bv = {0,0,0,0,0,0,0,0};
                if (lg < 2) bv = *(const bf16x8*)(qb + gj*256 + 128 + h*16 + lg*8);
                S[nt] = __builtin_amdgcn_mfma_f32_16x16x32_bf16(af, bv,
                            (f32x4){0.f,0.f,0.f,0.f}, 0, 0, 0);
            }
            // softmax
            float sm[4];
#pragma unroll
            for (int i = 0; i < 4; i++) {
                float m_ = -1e30f;
#pragma unroll
                for (int nt = 0; nt < 8; nt++) {
                    float v = S[nt][i] * 0.25f;
                    if (nt == 7 && ln15 >= 10) v = -1e30f;
                    S[nt][i] = v;
                    m_ = fmaxf(m_, v);
                }
                m_ = fmaxf(m_, __shfl_xor(m_, 1, 64));
                m_ = fmaxf(m_, __shfl_xor(m_, 2, 64));
                m_ = fmaxf(m_, __shfl_xor(m_, 4, 64));
                m_ = fmaxf(m_, __shfl_xor(m_, 8, 64));
                float s_ = 0.f;
#pragma unroll
                for (int nt = 0; nt < 8; nt++) {
                    float e = __expf(S[nt][i] - m_);
                    S[nt][i] = e;
                    s_ += e;
                }
                s_ += __shfl_xor(s_, 1, 64);
                s_ += __shfl_xor(s_, 2, 64);
                s_ += __shfl_xor(s_, 4, 64);
                s_ += __shfl_xor(s_, 8, 64);
                sm[i] = s_;
            }
            // P -> Pw (16 rows, A-layout)
#pragma unroll
            for (int nt = 0; nt < 8; nt++)
#pragma unroll
                for (int i = 0; i < 4; i++) {
                    int rp = lg*4 + i;
                    int j = nt*16 + ln15;
                    int cp = (j >> 3) ^ rp;
                    Pw[rp*128 + cp*8 + (j & 7)] = f2bf_hw(S[nt][i]);
                }
            // PV
            f32x4 cacc = (f32x4){0.f,0.f,0.f,0.f};
#pragma unroll
            for (int kt = 0; kt < 4; kt++) {
                bf16x8 bv = *(const bf16x8*)(vtb + ((size_t)(b*128 + h*16 + ln15))*128 + kt*32 + lg*8);
                int m = ln15;
                int cp = (kt*4 + lg) ^ m;
                bf16x8 ap = *(const bf16x8*)&Pw[m*128 + cp*8];
                cacc = __builtin_amdgcn_mfma_f32_16x16x32_bf16(ap, bv, cacc, 0, 0, 0);
            }
            // normalize + write ctx (bf16, A-layout)
#pragma unroll
            for (int i = 0; i < 4; i++) {
                float inv = __builtin_amdgcn_rcpf(sm[i]);
                int rp = mt*16 + lg*4 + i;
                int ccol = h*16 + ln15;
                int cp = (ccol >> 3) ^ (rp & 15);
                ctxs[rp*128 + cp*8 + (ccol & 7)] = f2bf_hw(cacc[i] * inv);
            }
        }
    }
    __syncthreads();

    // ================= out-proj + residual: wave w owns cols w*16..w*16+15 =================
    {
        f32x4 acc[2];
#pragma unroll
        for (int mi = 0; mi < 2; mi++) acc[mi] = (f32x4){0.f,0.f,0.f,0.f};
        int nn = w*16 + ln15;
#pragma unroll
        for (int kt = 0; kt < 4; kt++) {
            bf16x8 bv = *(const bf16x8*)&outW[(size_t)nn*128 + kt*32 + lg*8];
#pragma unroll
            for (int mi = 0; mi < 2; mi++) {
                int m = mi*16 + ln15;
                int cp = (kt*4 + lg) ^ (m & 15);
                bf16x8 afm = *(const bf16x8*)&ctxs[m*128 + cp*8];
                acc[mi] = __builtin_amdgcn_mfma_f32_16x16x32_bf16(afm, bv, acc[mi], 0, 0, 0);
            }
        }
        float bb = outb[nn];
#pragma unroll
        for (int mi = 0; mi < 2; mi++)
#pragma unroll
            for (int i = 0; i < 4; i++) {
                int ml = mi*16 + lg*4 + i;
                int mrow = m0l + ml;
                int grow = b*122 + ((mrow < 122) ? mrow : 121);
                Cs[ml*129 + nn] = acc[mi][i] + bb + tok[(size_t)grow*128 + nn];
            }
    }
    __syncthreads();

    // ================= LN1 -> Cs(f32) + ln1buf(bf16) =================
    unsigned short* ln1buf = Pregion;          // 8 KB
    unsigned short* Hs = Pregion + 4096;       // 16 KB
    {
        int r = tid >> 4, sub = tid & 15;      // 32 rows x 16 lanes x 8 cols
        float s1 = 0.f, s2 = 0.f;
#pragma unroll
        for (int j = 0; j < 8; j++) {
            float vv = Cs[r*129 + sub*8 + j];
            s1 += vv; s2 += vv*vv;
        }
        s1 += __shfl_xor(s1, 1, 64); s2 += __shfl_xor(s2, 1, 64);
        s1 += __shfl_xor(s1, 2, 64); s2 += __shfl_xor(s2, 2, 64);
        s1 += __shfl_xor(s1, 4, 64); s2 += __shfl_xor(s2, 4, 64);
        s1 += __shfl_xor(s1, 8, 64); s2 += __shfl_xor(s2, 8, 64);
        float mu = s1 * (1.0f/128.0f);
        float var = s2 * (1.0f/128.0f) - mu*mu;
        float rstd = rsqrtf(var + EPS);
#pragma unroll
        for (int j = 0; j < 8; j++) {
            int nloc = sub*8 + j;
            float vv = (Cs[r*129 + nloc] - mu) * rstd * ln1g[nloc] + ln1b[nloc];
            Cs[r*129 + nloc] = vv;
            int cp = (nloc >> 3) ^ (r & 15);
            ln1buf[r*128 + cp*8 + (nloc & 7)] = f2bf_hw(vv);
        }
    }
    __syncthreads();

    // ================= ff1 (gelu) -> Hs: wave w owns cols w*32..w*32+31 =================
    {
        f32x4 acc1[2][2];
#pragma unroll
        for (int mi = 0; mi < 2; mi++)
#pragma unroll
            for (int ni = 0; ni < 2; ni++) acc1[mi][ni] = (f32x4){0.f,0.f,0.f,0.f};
#pragma unroll
        for (int kt = 0; kt < 4; kt++) {
            bf16x8 afm[2];
#pragma unroll
            for (int mi = 0; mi < 2; mi++) {
                int m = mi*16 + ln15;
                int cp = (kt*4 + lg) ^ (m & 15);
                afm[mi] = *(const bf16x8*)&ln1buf[m*128 + cp*8];
            }
#pragma unroll
            for (int ni = 0; ni < 2; ni++) {
                int nn = (w*2 + ni)*16 + ln15;
                bf16x8 bv = *(const bf16x8*)&B1[(size_t)nn*128 + kt*32 + lg*8];
#pragma unroll
                for (int mi = 0; mi < 2; mi++)
                    acc1[mi][ni] = __builtin_amdgcn_mfma_f32_16x16x32_bf16(afm[mi], bv, acc1[mi][ni], 0, 0, 0);
            }
        }
#pragma unroll
        for (int ni = 0; ni < 2; ni++) {
            int nn = (w*2 + ni)*16 + ln15;
            float bb = b1[nn];
#pragma unroll
            for (int mi = 0; mi < 2; mi++)
#pragma unroll
                for (int i = 0; i < 4; i++) {
                    int m = mi*16 + lg*4 + i;
                    float v = gelu_fast(acc1[mi][ni][i] + bb);
                    int cp = (nn >> 3) ^ (m & 15);
                    Hs[m*256 + cp*8 + (nn & 7)] = f2bf_hw(v);
                }
        }
    }
    __syncthreads();

    // ================= ff2 + residual: wave w owns cols w*16..w*16+15 =================
    {
        f32x4 acc2[2];
#pragma unroll
        for (int mi = 0; mi < 2; mi++) acc2[mi] = (f32x4){0.f,0.f,0.f,0.f};
        int nn = w*16 + ln15;
#pragma unroll
        for (int kt = 0; kt < 8; kt++) {
            bf16x8 bv = *(const bf16x8*)&B2[(size_t)nn*256 + kt*32 + lg*8];
#pragma unroll
            for (int mi = 0; mi < 2; mi++) {
                int m = mi*16 + ln15;
                int cp = (kt*4 + lg) ^ (m & 15);
                bf16x8 afm = *(const bf16x8*)&Hs[m*256 + cp*8];
                acc2[mi] = __builtin_amdgcn_mfma_f32_16x16x32_bf16(afm, bv, acc2[mi], 0, 0, 0);
            }
        }
        float bb = b2[nn];
#pragma unroll
        for (int mi = 0; mi < 2; mi++)
#pragma unroll
            for (int i = 0; i < 4; i++) {
                int ml = mi*16 + lg*4 + i;
                Cs[ml*129 + nn] = acc2[mi][i] + bb + Cs[ml*129 + nn];
            }
    }
    __syncthreads();

    // ================= LN2 -> tok (+ qbuf staging for next-layer qkv) =================
    {
        int r = tid >> 4, sub = tid & 15;
        float s1 = 0.f, s2 = 0.f;
#pragma unroll
        for (int j = 0; j < 8; j++) {
            float vv = Cs[r*129 + sub*8 + j];
            s1 += vv; s2 += vv*vv;
        }
        s1 += __shfl_xor(s1, 1, 64); s2 += __shfl_xor(s2, 1, 64);
        s1 += __shfl_xor(s1, 2, 64); s2 += __shfl_xor(s2, 2, 64);
        s1 += __shfl_xor(s1, 4, 64); s2 += __shfl_xor(s2, 4, 64);
        s1 += __shfl_xor(s1, 8, 64); s2 += __shfl_xor(s2, 8, 64);
        float mu = s1 * (1.0f/128.0f);
        float var = s2 * (1.0f/128.0f) - mu*mu;
        float rstd = rsqrtf(var + EPS);
        bool rowok = (m0l + r < 122);
#pragma unroll
        for (int j = 0; j < 8; j++) {
            int nloc = sub*8 + j;
            float vv = (Cs[r*129 + nloc] - mu) * rstd * ln2g[nloc] + ln2b[nloc];
            if (rowok)
                tok[((size_t)(b*122 + m0l + r))*128 + nloc] = vv;
            if (do_qkv) {
                int cp = (nloc >> 3) ^ (r & 15);
                Pregion[r*128 + cp*8 + (nloc & 7)] = f2bf_hw(vv);
            }
        }
    }

    // ================= next-layer qkv: M=32, N=384, K=128; wave w owns cols w*48.. =====
    if (do_qkv) {
        __syncthreads();
        const unsigned short* qbuf = Pregion;
        f32x4 accq[2][3];
#pragma unroll
        for (int mi = 0; mi < 2; mi++)
#pragma unroll
            for (int ni = 0; ni < 3; ni++) accq[mi][ni] = (f32x4){0.f,0.f,0.f,0.f};
#pragma unroll
        for (int kt = 0; kt < 4; kt++) {
            bf16x8 afm[2];
#pragma unroll
            for (int mi = 0; mi < 2; mi++) {
                int m = mi*16 + ln15;
                int cp = (kt*4 + lg) ^ (m & 15);
                afm[mi] = *(const bf16x8*)&qbuf[m*128 + cp*8];
            }
#pragma unroll
            for (int ni = 0; ni < 3; ni++) {
                int e = w*48 + ni*16 + ln15;
                bf16x8 bv = *(const bf16x8*)&Bq[(size_t)e*128 + kt*32 + lg*8];
#pragma unroll
                for (int mi = 0; mi < 2; mi++)
                    accq[mi][ni] = __builtin_amdgcn_mfma_f32_16x16x32_bf16(afm[mi], bv, accq[mi][ni], 0, 0, 0);
            }
        }
#pragma unroll
        for (int ni = 0; ni < 3; ni++) {
            int e = w*48 + ni*16 + ln15;
            float bb = bq[e];
#pragma unroll
            for (int mi = 0; mi < 2; mi++)
#pragma unroll
                for (int i = 0; i < 4; i++) {
                    int ml = mi*16 + lg*4 + i;
                    int mrow = m0l + ml;
                    if (mrow < 122) {
                        unsigned short us = f2bf_hw(accq[mi][ni][i] + bb);
                        int nrow = b*122 + mrow;
                        if (e < 256)
                            qkvb_o[(size_t)nrow*256 + e] = us;
                        else
                            vtb_o[((size_t)(b*128 + (e - 256)))*128 + mrow] = us;
                    }
                }
        }
    }
}

// ---------------- final: mean over C + subject head ----------------
__global__ __launch_bounds__(128) void final_kernel(const float* __restrict__ tok,
        const int* __restrict__ sid,
        const float* __restrict__ hw, const float* __restrict__ hb,
        float* __restrict__ outp) {
    __shared__ float pool[DD];
    int b = blockIdx.x, tid = threadIdx.x;
    float s = 0.f;
    for (int c2 = 0; c2 < CC; c2++) s += tok[((size_t)b*CC + c2)*DD + tid];
    pool[tid] = s * (1.0f/(float)CC);
    __syncthreads();
    if (tid < 4) {
        int sb = sid[b];
        const float* w = hw + ((size_t)sb*4 + tid)*DD;
        float a = hb[sb*4 + tid];
#pragma unroll 8
        for (int d = 0; d < DD; d++) a = fmaf(pool[d], w[d], a);
        outp[b*4 + tid] = a;
    }
}

extern "C" void kernel_launch(void* const* d_in, const int* in_sizes, int n_in,
                              void* d_out, int out_size, void* d_ws, size_t ws_size,
                              hipStream_t stream) {
    const float* x       = (const float*)d_in[0];
    const int*   sid     = (const int*)  d_in[1];
    const float* conv1_w = (const float*)d_in[2];
    const float* conv1_b = (const float*)d_in[3];
    const float* bn1_g   = (const float*)d_in[4];
    const float* bn1_b   = (const float*)d_in[5];
    const float* bn1_m   = (const float*)d_in[6];
    const float* bn1_v   = (const float*)d_in[7];
    const float* conv2_w = (const float*)d_in[8];
    const float* conv2_b = (const float*)d_in[9];
    const float* bn2_g   = (const float*)d_in[10];
    const float* bn2_b   = (const float*)d_in[11];
    const float* bn2_m   = (const float*)d_in[12];
    const float* bn2_v   = (const float*)d_in[13];
    const float* proj_w  = (const float*)d_in[14];
    const float* proj_b  = (const float*)d_in[15];
    const float* elec    = (const float*)d_in[16];
    const float* qkv_w   = (const float*)d_in[17];
    const float* qkv_b   = (const float*)d_in[18];
    const float* out_w   = (const float*)d_in[19];
    const float* out_b   = (const float*)d_in[20];
    const float* ln1_g   = (const float*)d_in[21];
    const float* ln1_b   = (const float*)d_in[22];
    const float* ff1_w   = (const float*)d_in[23];
    const float* ff1_b   = (const float*)d_in[24];
    const float* ff2_w   = (const float*)d_in[25];
    const float* ff2_b   = (const float*)d_in[26];
    const float* ln2_g   = (const float*)d_in[27];
    const float* ln2_b   = (const float*)d_in[28];
    const float* heads_w = (const float*)d_in[29];
    const float* heads_b = (const float*)d_in[30];
    float* ws = (float*)d_ws;
    const unsigned short* wbf = (const unsigned short*)(ws + WS_WBF);
    unsigned short* qkvb  = (unsigned short*)(ws + WS_QKVB);
    unsigned short* vtb   = (unsigned short*)(ws + WS_VTB);
    unsigned short* qkvb2 = (unsigned short*)(ws + WS_QKVB2);
    unsigned short* vtb2  = (unsigned short*)(ws + WS_VTB2);

    prep_kernel<<<(293504 + 255)/256, 256, 0, stream>>>(
        conv1_w, conv1_b, bn1_g, bn1_b, bn1_m, bn1_v,
        conv2_w, conv2_b, bn2_g, bn2_b, bn2_m, bn2_v,
        qkv_w, out_w, ff1_w, ff2_w, proj_w, ws);

    conv_kernel<<<SEQ, 256, 0, stream>>>(x, proj_b, elec, ws, ws + WS_TOK);

    // layer-0 qkv
    qkv_gemm<<<dim3(244,3), 256, 0, stream>>>(
        ws + WS_TOK, wbf + WB_QKV, qkv_b, qkvb, vtb);

    // layer 0 (emits layer-1 qkv into double buffers)
    attn_tail<<<BB*4, 512, 0, stream>>>(
        qkvb, vtb,
        wbf + WB_OUT, out_b,
        ws + WS_TOK, ln1_g, ln1_b,
        wbf + WB_FF1, ff1_b,
        wbf + WB_FF2, ff2_b,
        ln2_g, ln2_b,
        wbf + WB_QKV + 49152, qkv_b + 384, qkvb2, vtb2, 1);

    // layer 1 (no next layer)
    attn_tail<<<BB*4, 512, 0, stream>>>(
        qkvb2, vtb2,
        wbf + WB_OUT + 16384, out_b + 128,
        ws + WS_TOK, ln1_g + 128, ln1_b + 128,
        wbf + WB_FF1 + 32768, ff1_b + 256,
        wbf + WB_FF2 + 32768, ff2_b + 128,
        ln2_g + 128, ln2_b + 128,
        wbf + WB_QKV, qkv_b, qkvb2, vtb2, 0);

    final_kernel<<<BB, 128, 0, stream>>>(ws + WS_TOK, sid, heads_w, heads_b, (float*)d_out);
}

// Round 11
// 408.213 us; speedup vs baseline: 2.2867x; 1.0276x over previous
//
#include <hip/hip_runtime.h>
#include <hip/hip_fp16.h>
#include <hip/hip_bf16.h>
#include <math.h>

#define BB 64
#define CC 122
#define TT 500
#define NCOUT 64
#define DD 128
#define HHEADS 8
#define FFDIM 256
#define NLAYER 2
#define EPS 1e-5f
#define SEQ (BB*CC)   // 7808

// ---------------- workspace float offsets ----------------
#define WS_W2T     0u            // 20480 ushort bf16 w2t [kk][co][ci] = 10240 floats used
#define WS_PWT     10240u        // 8192 floats: proj_w transposed [o][d] (free half of W2T rsv)
#define WS_S1      20480u
#define WS_SH1     20544u
#define WS_S2      20608u
#define WS_SH2     20672u
#define WS_WBF     20736u        // 262144 ushorts: bf16 qkv/out/ff1/ff2 weights
#define WS_TOK     151808u       // 7808*128 floats
#define WS_QKVB    1151232u      // 7808*256 ushorts (bf16 q,k) = 999424 floats
#define WS_VTB     2150656u      // 64*128*128 ushorts (bf16 v^T, [b][dh][j]) = 524288 floats
#define WS_GTAB    2674944u      // 512 uints: packed f16 (gelu, delta) pairs over [-8,8]
#define WS_W1S     2675968u      // 1024 floats: bf16 w1s[co][k=32], BN-folded
#define WS_QKVB2   2676992u      // layer-1 qkv double buffer (999424 floats)
#define WS_VTB2    3676416u      // layer-1 v^T double buffer (524288 floats)
// end = 4200704 floats = 16.8 MB

// WBF internal ushort offsets
#define WB_QKV  0u        // l*49152 + e*128 + k
#define WB_OUT  98304u    // l*16384 + e*128 + k
#define WB_FF1  131072u   // l*32768 + e*128 + k
#define WB_FF2  196608u   // l*32768 + e*256 + k

typedef __attribute__((ext_vector_type(8))) short bf16x8;
typedef __attribute__((ext_vector_type(4))) float f32x4;

__device__ __forceinline__ unsigned short f2bf(float f) {
    unsigned int u = __float_as_uint(f);
    unsigned int r = u + 0x7FFFu + ((u >> 16) & 1u);
    return (unsigned short)(r >> 16);
}

// hardware RNE f32->bf16 (gfx950 v_cvt_pk_bf16_f32), bit-identical to f2bf for finite x
__device__ __forceinline__ unsigned pk_bf16(float a, float b) {
    float r;
    asm("v_cvt_pk_bf16_f32 %0, %1, %2" : "=v"(r) : "v"(a), "v"(b));
    return __float_as_uint(r);
}
__device__ __forceinline__ unsigned short f2bf_hw(float f) {
    return (unsigned short)pk_bf16(f, f);
}

// branch-free erf-GELU (A&S 7.1.26)
__device__ __forceinline__ float gelu_fast(float x) {
    float z = fabsf(x) * 0.70710678118654752f;
    float t = __builtin_amdgcn_rcpf(fmaf(0.3275911f, z, 1.0f));
    float p = fmaf(fmaf(fmaf(fmaf(1.061405429f, t, -1.453152027f), t,
                             1.421413741f), t, -0.284496736f), t, 0.254829592f);
    float e = __expf(-z * z);
    float erf_abs = fmaf(-p * t, e, 1.0f);
    float erf_x = copysignf(erf_abs, x);
    return 0.5f * x * (1.0f + erf_x);
}

// table GELU on a pre-scaled index p = x*32+256 (BN folded by caller); 1 b32 gather
__device__ __forceinline__ float gelu_idx(float p, const unsigned* __restrict__ gt) {
    p = fminf(fmaxf(p, 0.0f), 511.999f);
    int i = (int)p;
    float fr = p - (float)i;
    unsigned u = gt[i];
    __half2 h2 = *(__half2*)&u;
    float v0 = __half2float(h2.x);
    float d  = __half2float(h2.y);
    return fmaf(fr, d, v0);
}

// h1s row swizzle. Writer (phase 1): r = w*64+lg*16+i*4+a+2 -> lane bits r>>4=lg0, r>>5=lg1;
// column contributes ln15b3 via co>>3. cp bits = {ln15b3, lg0, lg1} -> 32 banks, 2/bank (free).
// Reader (phase 2): r = base+ln15+kk -> r&7 lane-varying, <=2-way. Writer/reader must match.
__device__ __forceinline__ int swz3(int r) {
    return (r & 7) ^ (((r >> 4) & 1) << 1) ^ (((r >> 5) & 1) << 2);
}

// ---------------- prep: fold BN, bf16-ify weights, build tables ----------------
__global__ void prep_kernel(const float* __restrict__ conv1_w, const float* __restrict__ conv1_b,
                            const float* __restrict__ bn1_g, const float* __restrict__ bn1_b,
                            const float* __restrict__ bn1_m, const float* __restrict__ bn1_v,
                            const float* __restrict__ conv2_w, const float* __restrict__ conv2_b,
                            const float* __restrict__ bn2_g, const float* __restrict__ bn2_b,
                            const float* __restrict__ bn2_m, const float* __restrict__ bn2_v,
                            const float* __restrict__ qkv_w, const float* __restrict__ out_w,
                            const float* __restrict__ ff1_w, const float* __restrict__ ff2_w,
                            const float* __restrict__ proj_w,
                            float* __restrict__ ws) {
    int idx = blockIdx.x * blockDim.x + threadIdx.x;
    if (idx < 20480) {
        int ci = idx & 63; int co = (idx >> 6) & 63; int kk = idx >> 12;
        unsigned short* wt = (unsigned short*)(ws + WS_W2T);
        wt[idx] = f2bf(conv2_w[(co*64 + ci)*5 + kk]);
    } else if (idx < 20544) {
        int i = idx - 20480;
        float s = bn1_g[i] * rsqrtf(bn1_v[i] + EPS);
        ws[WS_S1 + i] = s;
        ws[WS_SH1 + i] = (conv1_b[i] - bn1_m[i]) * s + bn1_b[i];
    } else if (idx < 20608) {
        int i = idx - 20544;
        float s = bn2_g[i] * rsqrtf(bn2_v[i] + EPS);
        ws[WS_S2 + i] = s;
        ws[WS_SH2 + i] = (conv2_b[i] - bn2_m[i]) * s + bn2_b[i];
    } else if (idx < 282752) {
        int r = idx - 20608;
        unsigned short* wbf = (unsigned short*)(ws + WS_WBF);
        float v;
        if (r < 98304)       v = qkv_w[r];
        else if (r < 131072) v = out_w[r - 98304];
        else if (r < 196608) v = ff1_w[r - 131072];
        else                 v = ff2_w[r - 196608];
        wbf[r] = f2bf(v);
    } else if (idx < 283264) {
        int i = idx - 282752;
        float x0 = (i - 256) * 0.03125f;
        float x1 = x0 + 0.03125f;
        float g0 = 0.5f*x0*(1.0f + erff(x0*0.70710678118654752f));
        float g1 = 0.5f*x1*(1.0f + erff(x1*0.70710678118654752f));
        __half hv = __float2half_rn(g0);
        __half hd = __float2half_rn(g1 - g0);
        unsigned short uv = *(unsigned short*)&hv;
        unsigned short ud = *(unsigned short*)&hd;
        ((unsigned*)(ws + WS_GTAB))[i] = (unsigned)uv | ((unsigned)ud << 16);
    } else if (idx < 285312) {
        int i = idx - 283264;            // co*32 + k
        int co = i >> 5, k = i & 31;
        unsigned short* w1s = (unsigned short*)(ws + WS_W1S);
        float s = bn1_g[co] * rsqrtf(bn1_v[co] + EPS);
        w1s[i] = (k < 9) ? f2bf(conv1_w[co*9 + k] * s) : (unsigned short)0;
    } else if (idx < 293504) {
        int i = idx - 285312;            // o*128 + d
        int o = i >> 7, d = i & 127;
        ws[WS_PWT + i] = proj_w[d*64 + o];   // transpose for coalesced conv epilogue
    }
}

// ---------------- fused conv1 [MFMA] + pool + conv2 [MFMA] + mean + proj ----------------
// R4 structure, frozen (session-best conv 256.5us). Chunked-T variants (R7-R9) all spilled
// ~2 GB/dispatch regardless of launch_bounds/acc size -- do not retry chunking at HIP level.
__global__ __launch_bounds__(256, 4) void conv_kernel(const float* __restrict__ x,
            const float* __restrict__ proj_b,
            const float* __restrict__ elec,
            const float* __restrict__ wsr, float* __restrict__ tok) {
    __shared__ __align__(16) unsigned short h1s[264*64];  // 33792 B
    __shared__ __align__(16) unsigned short xbf[544];     // 1088 B
    __shared__ __align__(16) unsigned gtab[512];          // 2048 B (packed f16 pairs)
    __shared__ float part[256];                           // 1024 B
    __shared__ float mean_l[64];                          // 256 B
    int n = blockIdx.x;
    int c = n % CC;
    int tid = threadIdx.x;
    const float* xg = x + (size_t)n * TT;

    for (int i = tid; i < 544; i += 256) {
        unsigned short v = 0;
        if (i >= 4 && i < 504) v = f2bf_hw(xg[i-4]);
        xbf[i] = v;
    }
    if (tid < 128) {
        ((uint4*)gtab)[tid] = ((const uint4*)(wsr + WS_GTAB))[tid];
    }
    for (int idx = tid; idx < 14*64; idx += 256) {
        int rr = idx >> 6;
        int r = (rr < 2) ? rr : (rr - 2 + 252);
        h1s[r*64 + (idx & 63)] = 0;
    }
    __syncthreads();

    int lane = tid & 63;
    int w = tid >> 6;
    int ln15 = lane & 15, lg = lane >> 4;

    // ---- phase 1: conv1 via MFMA, strided-row im2col ----
    {
        const unsigned short* w1s = (const unsigned short*)(wsr + WS_W1S);
        bf16x8 b1f[4];
        float shp[4];
#pragma unroll
        for (int nt = 0; nt < 4; nt++) {
            int co = nt*16 + ln15;
            b1f[nt] = *(const bf16x8*)&w1s[co*32 + lg*8];
            shp[nt] = fmaf(wsr[WS_SH1 + co], 32.0f, 256.0f);
        }
        int P = w*128 + ln15*8 + lg*8;
        uint4 Va = *(const uint4*)&xbf[P];
        uint4 Vb = *(const uint4*)&xbf[P + 8];
        unsigned vwin[8] = {Va.x, Va.y, Va.z, Va.w, Vb.x, Vb.y, Vb.z, Vb.w};
#pragma unroll
        for (int a = 0; a < 4; a++) {
            union { unsigned u[4]; bf16x8 b; } Ue, Uo;
#pragma unroll
            for (int d = 0; d < 4; d++) {
                Ue.u[d] = vwin[a + d];
                Uo.u[d] = (vwin[a + d] >> 16) | (vwin[a + d + 1] << 16);
            }
            f32x4 ce[4], cod[4];
#pragma unroll
            for (int nt = 0; nt < 4; nt++) {
                ce[nt]  = __builtin_amdgcn_mfma_f32_16x16x32_bf16(Ue.b, b1f[nt],
                              (f32x4){0.f,0.f,0.f,0.f}, 0, 0, 0);
                cod[nt] = __builtin_amdgcn_mfma_f32_16x16x32_bf16(Uo.b, b1f[nt],
                              (f32x4){0.f,0.f,0.f,0.f}, 0, 0, 0);
            }
#pragma unroll
            for (int nt = 0; nt < 4; nt++) {
                int co = nt*16 + ln15;
#pragma unroll
                for (int i = 0; i < 4; i++) {
                    int tp = w*64 + lg*16 + i*4 + a;
                    if (tp < 250) {
                        float ge = gelu_idx(fmaf(ce[nt][i],  32.0f, shp[nt]), gtab);
                        float go = gelu_idx(fmaf(cod[nt][i], 32.0f, shp[nt]), gtab);
                        int r = tp + 2;
                        int cp = (co >> 3) ^ swz3(r);
                        h1s[r*64 + cp*8 + (co & 7)] = f2bf_hw(fmaxf(ge, go));
                    }
                }
            }
        }
    }
    __syncthreads();

    // ---- phase 2: conv2 as 5 shifted GEMMs ----
    const unsigned short* wt = (const unsigned short*)(wsr + WS_W2T);
    f32x4 acc[4][4];
#pragma unroll
    for (int mi = 0; mi < 4; mi++)
#pragma unroll
        for (int nt = 0; nt < 4; nt++) acc[mi][nt] = (f32x4){0.f, 0.f, 0.f, 0.f};

    const unsigned short* wbase = wt + ln15*64 + lg*8;
#pragma unroll
    for (int kk = 0; kk < 5; kk++) {
#pragma unroll
        for (int s = 0; s < 2; s++) {
            bf16x8 bfv[4];
#pragma unroll
            for (int nt = 0; nt < 4; nt++)
                bfv[nt] = *(const bf16x8*)(wbase + kk*4096 + nt*1024 + s*32);
#pragma unroll
            for (int mi = 0; mi < 4; mi++) {
                int r = (w*4 + mi)*16 + ln15 + kk;
                int cp = (s*4 + lg) ^ swz3(r);
                bf16x8 af = *(const bf16x8*)&h1s[r*64 + cp*8];
#pragma unroll
                for (int nt = 0; nt < 4; nt++)
                    acc[mi][nt] = __builtin_amdgcn_mfma_f32_16x16x32_bf16(af, bfv[nt], acc[mi][nt], 0, 0, 0);
            }
        }
    }

    // ---- epilogue: BN + GELU + mean over t ----
#pragma unroll
    for (int nt = 0; nt < 4; nt++) {
        int co2 = nt*16 + ln15;
        float sc = wsr[WS_S2 + co2] * 32.0f;
        float sh = fmaf(wsr[WS_SH2 + co2], 32.0f, 256.0f);
        float p = 0.f;
#pragma unroll
        for (int mi = 0; mi < 4; mi++) {
            int tbase = (w*4 + mi)*16 + lg*4;
#pragma unroll
            for (int i = 0; i < 4; i++) {
                if (tbase + i < 250)
                    p += gelu_idx(fmaf(acc[mi][nt][i], sc, sh), gtab);
            }
        }
        p += __shfl_down(p, 32, 64);
        p += __shfl_down(p, 16, 64);
        if (lane < 16) part[w*64 + co2] = p;
    }
    __syncthreads();
    if (tid < 64) {
        mean_l[tid] = (part[tid] + part[64+tid] + part[128+tid] + part[192+tid]) * (1.0f/250.0f);
    }
    __syncthreads();

    if (tid < DD) {
        int d = tid;
        const float* pwt = wsr + WS_PWT;
        float a = proj_b[d] + elec[c*DD + d];
#pragma unroll 8
        for (int o = 0; o < 64; o++) a = fmaf(mean_l[o], pwt[o*128 + d], a);
        tok[(size_t)n * DD + d] = a;
    }
}

// ---------------- qkv GEMM (layer 0 only): tok[f32] @ qkv_w^T + b -> bf16 qkvb / vtb ----
__global__ __launch_bounds__(256) void qkv_gemm(const float* __restrict__ Aptr,
        const unsigned short* __restrict__ Bbf,
        const float* __restrict__ bias,
        unsigned short* __restrict__ qkvb,        // [7808][256]
        unsigned short* __restrict__ vtb) {       // [b*128+dh][128]
    const int tid = threadIdx.x;
    const int m0 = blockIdx.x * 32;
    const int y  = blockIdx.y;                    // 0:q 1:k 2:v
    const int n0 = y * 128;
    __shared__ __align__(16) unsigned short As[32*128];

    const float* A = Aptr + (size_t)m0 * 128;
    for (int i = tid; i < 1024; i += 256) {
        int m = i >> 5; int kq = (i & 31)*4;
        float4 v = *(const float4*)(A + m*128 + kq);
        int cp = (kq >> 3) ^ (m & 15);
        unsigned p0 = pk_bf16(v.x, v.y);
        unsigned p1 = pk_bf16(v.z, v.w);
        *(uint2*)&As[m*128 + cp*8 + (kq & 7)] = make_uint2(p0, p1);
    }
    __syncthreads();

    const int lane = tid & 63, w = tid >> 6;
    const int ln15 = lane & 15, lg = lane >> 4;
    f32x4 acc[2][2];
#pragma unroll
    for (int mi = 0; mi < 2; mi++)
#pragma unroll
        for (int ni = 0; ni < 2; ni++) acc[mi][ni] = (f32x4){0.f, 0.f, 0.f, 0.f};

    const unsigned short* Bb = Bbf + (size_t)n0 * 128;
#pragma unroll
    for (int kt = 0; kt < 4; kt++) {
        bf16x8 af[2], bfv[2];
#pragma unroll
        for (int mi = 0; mi < 2; mi++) {
            int m = mi*16 + ln15;
            int cp = (kt*4 + lg) ^ (m & 15);
            af[mi] = *(const bf16x8*)&As[m*128 + cp*8];
        }
#pragma unroll
        for (int ni = 0; ni < 2; ni++) {
            int nn = (w*2 + ni)*16 + ln15;
            bfv[ni] = *(const bf16x8*)&Bb[(size_t)nn*128 + kt*32 + lg*8];
        }
#pragma unroll
        for (int mi = 0; mi < 2; mi++)
#pragma unroll
            for (int ni = 0; ni < 2; ni++)
                acc[mi][ni] = __builtin_amdgcn_mfma_f32_16x16x32_bf16(af[mi], bfv[ni], acc[mi][ni], 0, 0, 0);
    }

#pragma unroll
    for (int mi = 0; mi < 2; mi++)
#pragma unroll
        for (int ni = 0; ni < 2; ni++) {
            int nloc = (w*2 + ni)*16 + ln15;
            float bb = bias[n0 + nloc];
#pragma unroll
            for (int i = 0; i < 4; i++) {
                int ml = mi*16 + lg*4 + i;
                int nrow = m0 + ml;
                unsigned short us = f2bf_hw(acc[mi][ni][i] + bb);
                if (y < 2) {
                    qkvb[(size_t)nrow*256 + n0 + nloc] = us;
                } else {
                    int bq = nrow / 122;
                    int j  = nrow - bq*122;
                    vtb[((size_t)(bq*128 + nloc))*128 + j] = us;
                }
            }
        }
}

// ---------------- fused attention + out-proj + LN1 + FF + LN2 (+ next-layer qkv) ----------
// round-11: 16-row blocks (grid BB*8 = 512) instead of 32-row (256). Old grid = 1 block/CU
// (grid-limited, NOT resource-limited: 56.5 KB LDS would fit 2). New: 2 blocks/CU resident,
// 16 waves/CU (50% occ); two independent blocks overlap across each other's barriers.
// All GEMM phases M=32 -> M=16 (one M-tile); LN phases 16 rows x 32 threads. LDS 44.25 KB.
__global__ __launch_bounds__(512) void attn_tail(
        const unsigned short* __restrict__ qkvb,
        const unsigned short* __restrict__ vtb,
        const unsigned short* __restrict__ outW, const float* __restrict__ outb,
        float* __restrict__ tok,
        const float* __restrict__ ln1g, const float* __restrict__ ln1b,
        const unsigned short* __restrict__ B1, const float* __restrict__ b1,
        const unsigned short* __restrict__ B2, const float* __restrict__ b2,
        const float* __restrict__ ln2g, const float* __restrict__ ln2b,
        const unsigned short* __restrict__ Bq, const float* __restrict__ bq,
        unsigned short* __restrict__ qkvb_o, unsigned short* __restrict__ vtb_o,
        int do_qkv) {
    __shared__ float Cs[16*129];                               // 8.25 KB
    __shared__ __align__(16) unsigned short Pregion[8*16*128]; // 32 KB (P/wave; later ln1buf+Hs; later qbuf)
    __shared__ __align__(16) unsigned short ctxs[16*128];      // 4 KB

    const int tid = threadIdx.x;
    const int blk = blockIdx.x;
    const int b = blk >> 3, mq = blk & 7;
    const int m0l = mq * 16;                       // rows m0l..m0l+15
    const int lane = tid & 63, w = tid >> 6;       // w = 0..7 = head
    const int ln15 = lane & 15, lg = lane >> 4;

    const unsigned short* qb = qkvb + (size_t)b * 122 * 256;
    unsigned short* Pw = Pregion + w * 2048;       // 16 rows x 128 cols bf16

    // ================= attention: head h = w, one 16-row chunk =================
    {
        const int h = w;
        int mrow = m0l + ln15;
        int gr = (mrow < 122) ? mrow : 121;
        bf16x8 af = {0,0,0,0,0,0,0,0};
        if (lg < 2) af = *(const bf16x8*)(qb + gr*256 + h*16 + lg*8);
        // S = Q K^T
        f32x4 S[8];
#pragma unroll
        for (int nt = 0; nt < 8; nt++) {
            int j = nt*16 + ln15;
            int gj = (j < 122) ? j : 121;
            bf16x8 bv = {0,0,0,0,0,0,0,0};
            if (lg < 2) bv = *(const bf16x8*)(qb + gj*256 + 128 + h*16 + lg*8);
            S[nt] = __builtin_amdgcn_mfma_f32_16x16x32_bf16(af, bv,
                        (f32x4){0.f,0.f,0.f,0.f}, 0, 0, 0);
        }
        // softmax
        float sm[4];
#pragma unroll
        for (int i = 0; i < 4; i++) {
            float m_ = -1e30f;
#pragma unroll
            for (int nt = 0; nt < 8; nt++) {
                float v = S[nt][i] * 0.25f;
                if (nt == 7 && ln15 >= 10) v = -1e30f;
                S[nt][i] = v;
                m_ = fmaxf(m_, v);
            }
            m_ = fmaxf(m_, __shfl_xor(m_, 1, 64));
            m_ = fmaxf(m_, __shfl_xor(m_, 2, 64));
            m_ = fmaxf(m_, __shfl_xor(m_, 4, 64));
            m_ = fmaxf(m_, __shfl_xor(m_, 8, 64));
            float s_ = 0.f;
#pragma unroll
            for (int nt = 0; nt < 8; nt++) {
                float e = __expf(S[nt][i] - m_);
                S[nt][i] = e;
                s_ += e;
            }
            s_ += __shfl_xor(s_, 1, 64);
            s_ += __shfl_xor(s_, 2, 64);
            s_ += __shfl_xor(s_, 4, 64);
            s_ += __shfl_xor(s_, 8, 64);
            sm[i] = s_;
        }
        // P -> Pw (16 rows, A-layout)
#pragma unroll
        for (int nt = 0; nt < 8; nt++)
#pragma unroll
            for (int i = 0; i < 4; i++) {
                int rp = lg*4 + i;
                int j = nt*16 + ln15;
                int cp = (j >> 3) ^ rp;
                Pw[rp*128 + cp*8 + (j & 7)] = f2bf_hw(S[nt][i]);
            }
        // PV
        f32x4 cacc = (f32x4){0.f,0.f,0.f,0.f};
#pragma unroll
        for (int kt = 0; kt < 4; kt++) {
            bf16x8 bv = *(const bf16x8*)(vtb + ((size_t)(b*128 + h*16 + ln15))*128 + kt*32 + lg*8);
            int m = ln15;
            int cp = (kt*4 + lg) ^ m;
            bf16x8 ap = *(const bf16x8*)&Pw[m*128 + cp*8];
            cacc = __builtin_amdgcn_mfma_f32_16x16x32_bf16(ap, bv, cacc, 0, 0, 0);
        }
        // normalize + write ctx (bf16, A-layout)
#pragma unroll
        for (int i = 0; i < 4; i++) {
            float inv = __builtin_amdgcn_rcpf(sm[i]);
            int rp = lg*4 + i;
            int ccol = h*16 + ln15;
            int cp = (ccol >> 3) ^ (rp & 15);
            ctxs[rp*128 + cp*8 + (ccol & 7)] = f2bf_hw(cacc[i] * inv);
        }
    }
    __syncthreads();

    // ================= out-proj + residual: wave w owns cols w*16..w*16+15 =================
    {
        f32x4 acc = (f32x4){0.f,0.f,0.f,0.f};
        int nn = w*16 + ln15;
#pragma unroll
        for (int kt = 0; kt < 4; kt++) {
            bf16x8 bv = *(const bf16x8*)&outW[(size_t)nn*128 + kt*32 + lg*8];
            int m = ln15;
            int cp = (kt*4 + lg) ^ (m & 15);
            bf16x8 afm = *(const bf16x8*)&ctxs[m*128 + cp*8];
            acc = __builtin_amdgcn_mfma_f32_16x16x32_bf16(afm, bv, acc, 0, 0, 0);
        }
        float bb = outb[nn];
#pragma unroll
        for (int i = 0; i < 4; i++) {
            int ml = lg*4 + i;
            int mrow = m0l + ml;
            int grow = b*122 + ((mrow < 122) ? mrow : 121);
            Cs[ml*129 + nn] = acc[i] + bb + tok[(size_t)grow*128 + nn];
        }
    }
    __syncthreads();

    // ================= LN1 -> Cs(f32) + ln1buf(bf16): 16 rows x 32 threads =================
    unsigned short* ln1buf = Pregion;          // 4 KB (2048 ushorts)
    unsigned short* Hs = Pregion + 2048;       // 8 KB (4096 ushorts)
    {
        int r = tid >> 5, sub = tid & 31;      // 16 rows x 32 lanes x 4 cols
        float s1 = 0.f, s2 = 0.f;
#pragma unroll
        for (int j = 0; j < 4; j++) {
            float vv = Cs[r*129 + sub*4 + j];
            s1 += vv; s2 += vv*vv;
        }
        s1 += __shfl_xor(s1, 1, 64);  s2 += __shfl_xor(s2, 1, 64);
        s1 += __shfl_xor(s1, 2, 64);  s2 += __shfl_xor(s2, 2, 64);
        s1 += __shfl_xor(s1, 4, 64);  s2 += __shfl_xor(s2, 4, 64);
        s1 += __shfl_xor(s1, 8, 64);  s2 += __shfl_xor(s2, 8, 64);
        s1 += __shfl_xor(s1, 16, 64); s2 += __shfl_xor(s2, 16, 64);
        float mu = s1 * (1.0f/128.0f);
        float var = s2 * (1.0f/128.0f) - mu*mu;
        float rstd = rsqrtf(var + EPS);
#pragma unroll
        for (int j = 0; j < 4; j++) {
            int nloc = sub*4 + j;
            float vv = (Cs[r*129 + nloc] - mu) * rstd * ln1g[nloc] + ln1b[nloc];
            Cs[r*129 + nloc] = vv;
            int cp = (nloc >> 3) ^ (r & 15);
            ln1buf[r*128 + cp*8 + (nloc & 7)] = f2bf_hw(vv);
        }
    }
    __syncthreads();

    // ================= ff1 (gelu) -> Hs: wave w owns cols w*32..w*32+31 =================
    {
        f32x4 acc1[2];
#pragma unroll
        for (int ni = 0; ni < 2; ni++) acc1[ni] = (f32x4){0.f,0.f,0.f,0.f};
#pragma unroll
        for (int kt = 0; kt < 4; kt++) {
            int m = ln15;
            int cp = (kt*4 + lg) ^ (m & 15);
            bf16x8 afm = *(const bf16x8*)&ln1buf[m*128 + cp*8];
#pragma unroll
            for (int ni = 0; ni < 2; ni++) {
                int nn = (w*2 + ni)*16 + ln15;
                bf16x8 bv = *(const bf16x8*)&B1[(size_t)nn*128 + kt*32 + lg*8];
                acc1[ni] = __builtin_amdgcn_mfma_f32_16x16x32_bf16(afm, bv, acc1[ni], 0, 0, 0);
            }
        }
#pragma unroll
        for (int ni = 0; ni < 2; ni++) {
            int nn = (w*2 + ni)*16 + ln15;
            float bb = b1[nn];
#pragma unroll
            for (int i = 0; i < 4; i++) {
                int m = lg*4 + i;
                float v = gelu_fast(acc1[ni][i] + bb);
                int cp = (nn >> 3) ^ (m & 15);
                Hs[m*256 + cp*8 + (nn & 7)] = f2bf_hw(v);
            }
        }
    }
    __syncthreads();

    // ================= ff2 + residual: wave w owns cols w*16..w*16+15 =================
    {
        f32x4 acc2 = (f32x4){0.f,0.f,0.f,0.f};
        int nn = w*16 + ln15;
#pragma unroll
        for (int kt = 0; kt < 8; kt++) {
            bf16x8 bv = *(const bf16x8*)&B2[(size_t)nn*256 + kt*32 + lg*8];
            int m = ln15;
            int cp = (kt*4 + lg) ^ (m & 15);
            bf16x8 afm = *(const bf16x8*)&Hs[m*256 + cp*8];
            acc2 = __builtin_amdgcn_mfma_f32_16x16x32_bf16(afm, bv, acc2, 0, 0, 0);
        }
        float bb = b2[nn];
#pragma unroll
        for (int i = 0; i < 4; i++) {
            int ml = lg*4 + i;
            Cs[ml*129 + nn] = acc2[i] + bb + Cs[ml*129 + nn];
        }
    }
    __syncthreads();

    // ================= LN2 -> tok (+ qbuf staging for next-layer qkv) =================
    {
        int r = tid >> 5, sub = tid & 31;
        float s1 = 0.f, s2 = 0.f;
#pragma unroll
        for (int j = 0; j < 4; j++) {
            float vv = Cs[r*129 + sub*4 + j];
            s1 += vv; s2 += vv*vv;
        }
        s1 += __shfl_xor(s1, 1, 64);  s2 += __shfl_xor(s2, 1, 64);
        s1 += __shfl_xor(s1, 2, 64);  s2 += __shfl_xor(s2, 2, 64);
        s1 += __shfl_xor(s1, 4, 64);  s2 += __shfl_xor(s2, 4, 64);
        s1 += __shfl_xor(s1, 8, 64);  s2 += __shfl_xor(s2, 8, 64);
        s1 += __shfl_xor(s1, 16, 64); s2 += __shfl_xor(s2, 16, 64);
        float mu = s1 * (1.0f/128.0f);
        float var = s2 * (1.0f/128.0f) - mu*mu;
        float rstd = rsqrtf(var + EPS);
        bool rowok = (m0l + r < 122);
#pragma unroll
        for (int j = 0; j < 4; j++) {
            int nloc = sub*4 + j;
            float vv = (Cs[r*129 + nloc] - mu) * rstd * ln2g[nloc] + ln2b[nloc];
            if (rowok)
                tok[((size_t)(b*122 + m0l + r))*128 + nloc] = vv;
            if (do_qkv) {
                int cp = (nloc >> 3) ^ (r & 15);
                Pregion[r*128 + cp*8 + (nloc & 7)] = f2bf_hw(vv);
            }
        }
    }

    // ================= next-layer qkv: M=16, N=384, K=128; wave w owns cols w*48.. =====
    if (do_qkv) {
        __syncthreads();
        const unsigned short* qbuf = Pregion;
        f32x4 accq[3];
#pragma unroll
        for (int ni = 0; ni < 3; ni++) accq[ni] = (f32x4){0.f,0.f,0.f,0.f};
#pragma unroll
        for (int kt = 0; kt < 4; kt++) {
            int m = ln15;
            int cp = (kt*4 + lg) ^ (m & 15);
            bf16x8 afm = *(const bf16x8*)&qbuf[m*128 + cp*8];
#pragma unroll
            for (int ni = 0; ni < 3; ni++) {
                int e = w*48 + ni*16 + ln15;
                bf16x8 bv = *(const bf16x8*)&Bq[(size_t)e*128 + kt*32 + lg*8];
                accq[ni] = __builtin_amdgcn_mfma_f32_16x16x32_bf16(afm, bv, accq[ni], 0, 0, 0);
            }
        }
#pragma unroll
        for (int ni = 0; ni < 3; ni++) {
            int e = w*48 + ni*16 + ln15;
            float bb = bq[e];
#pragma unroll
            for (int i = 0; i < 4; i++) {
                int ml = lg*4 + i;
                int mrow = m0l + ml;
                if (mrow < 122) {
                    unsigned short us = f2bf_hw(accq[ni][i] + bb);
                    int nrow = b*122 + mrow;
                    if (e < 256)
                        qkvb_o[(size_t)nrow*256 + e] = us;
                    else
                        vtb_o[((size_t)(b*128 + (e - 256)))*128 + mrow] = us;
                }
            }
        }
    }
}

// ---------------- final: mean over C + subject head (4-way c-split) ----------------
__global__ __launch_bounds__(512) void final_kernel(const float* __restrict__ tok,
        const int* __restrict__ sid,
        const float* __restrict__ hw, const float* __restrict__ hb,
        float* __restrict__ outp) {
    __shared__ float pool[4][DD];
    __shared__ float pooled[DD];
    int b = blockIdx.x, tid = threadIdx.x;
    int q = tid >> 7, d = tid & 127;
    float s = 0.f;
    for (int c2 = q; c2 < CC; c2 += 4) s += tok[((size_t)b*CC + c2)*DD + d];
    pool[q][d] = s;
    __syncthreads();
    if (tid < DD)
        pooled[tid] = (pool[0][tid] + pool[1][tid] + pool[2][tid] + pool[3][tid])
                      * (1.0f/(float)CC);
    __syncthreads();
    if (tid < 4) {
        int sb = sid[b];
        const float* w = hw + ((size_t)sb*4 + tid)*DD;
        float a = hb[sb*4 + tid];
#pragma unroll 8
        for (int d2 = 0; d2 < DD; d2++) a = fmaf(pooled[d2], w[d2], a);
        outp[b*4 + tid] = a;
    }
}

extern "C" void kernel_launch(void* const* d_in, const int* in_sizes, int n_in,
                              void* d_out, int out_size, void* d_ws, size_t ws_size,
                              hipStream_t stream) {
    const float* x       = (const float*)d_in[0];
    const int*   sid     = (const int*)  d_in[1];
    const float* conv1_w = (const float*)d_in[2];
    const float* conv1_b = (const float*)d_in[3];
    const float* bn1_g   = (const float*)d_in[4];
    const float* bn1_b   = (const float*)d_in[5];
    const float* bn1_m   = (const float*)d_in[6];
    const float* bn1_v   = (const float*)d_in[7];
    const float* conv2_w = (const float*)d_in[8];
    const float* conv2_b = (const float*)d_in[9];
    const float* bn2_g   = (const float*)d_in[10];
    const float* bn2_b   = (const float*)d_in[11];
    const float* bn2_m   = (const float*)d_in[12];
    const float* bn2_v   = (const float*)d_in[13];
    const float* proj_w  = (const float*)d_in[14];
    const float* proj_b  = (const float*)d_in[15];
    const float* elec    = (const float*)d_in[16];
    const float* qkv_w   = (const float*)d_in[17];
    const float* qkv_b   = (const float*)d_in[18];
    const float* out_w   = (const float*)d_in[19];
    const float* out_b   = (const float*)d_in[20];
    const float* ln1_g   = (const float*)d_in[21];
    const float* ln1_b   = (const float*)d_in[22];
    const float* ff1_w   = (const float*)d_in[23];
    const float* ff1_b   = (const float*)d_in[24];
    const float* ff2_w   = (const float*)d_in[25];
    const float* ff2_b   = (const float*)d_in[26];
    const float* ln2_g   = (const float*)d_in[27];
    const float* ln2_b   = (const float*)d_in[28];
    const float* heads_w = (const float*)d_in[29];
    const float* heads_b = (const float*)d_in[30];
    float* ws = (float*)d_ws;
    const unsigned short* wbf = (const unsigned short*)(ws + WS_WBF);
    unsigned short* qkvb  = (unsigned short*)(ws + WS_QKVB);
    unsigned short* vtb   = (unsigned short*)(ws + WS_VTB);
    unsigned short* qkvb2 = (unsigned short*)(ws + WS_QKVB2);
    unsigned short* vtb2  = (unsigned short*)(ws + WS_VTB2);

    prep_kernel<<<(293504 + 255)/256, 256, 0, stream>>>(
        conv1_w, conv1_b, bn1_g, bn1_b, bn1_m, bn1_v,
        conv2_w, conv2_b, bn2_g, bn2_b, bn2_m, bn2_v,
        qkv_w, out_w, ff1_w, ff2_w, proj_w, ws);

    conv_kernel<<<SEQ, 256, 0, stream>>>(x, proj_b, elec, ws, ws + WS_TOK);

    // layer-0 qkv
    qkv_gemm<<<dim3(244,3), 256, 0, stream>>>(
        ws + WS_TOK, wbf + WB_QKV, qkv_b, qkvb, vtb);

    // layer 0 (emits layer-1 qkv into double buffers)
    attn_tail<<<BB*8, 512, 0, stream>>>(
        qkvb, vtb,
        wbf + WB_OUT, out_b,
        ws + WS_TOK, ln1_g, ln1_b,
        wbf + WB_FF1, ff1_b,
        wbf + WB_FF2, ff2_b,
        ln2_g, ln2_b,
        wbf + WB_QKV + 49152, qkv_b + 384, qkvb2, vtb2, 1);

    // layer 1 (no next layer)
    attn_tail<<<BB*8, 512, 0, stream>>>(
        qkvb2, vtb2,
        wbf + WB_OUT + 16384, out_b + 128,
        ws + WS_TOK, ln1_g + 128, ln1_b + 128,
        wbf + WB_FF1 + 32768, ff1_b + 256,
        wbf + WB_FF2 + 32768, ff2_b + 128,
        ln2_g + 128, ln2_b + 128,
        wbf + WB_QKV, qkv_b, qkvb2, vtb2, 0);

    final_kernel<<<BB, 512, 0, stream>>>(ws + WS_TOK, sid, heads_w, heads_b, (float*)d_out);
}